// Round 6
// baseline (505.540 us; speedup 1.0000x reference)
//
#include <hip/hip_runtime.h>
#include <hip/hip_bf16.h>
#include <math.h>

typedef __bf16 bf16;
typedef bf16 bf16x8 __attribute__((ext_vector_type(8)));
typedef bf16 bf16x4 __attribute__((ext_vector_type(4)));
typedef float f32x4 __attribute__((ext_vector_type(4)));

#define MFMA16(a, b, c) __builtin_amdgcn_mfma_f32_16x16x32_bf16(a, b, c, 0, 0, 0)

// XOR-swizzle on 16B chunks within a row: breaks power-of-2 row-stride bank aliasing.
__device__ __forceinline__ uint32_t swz(uint32_t base, uint32_t row, uint32_t rs, uint32_t cb) {
    return base + row * rs + (((cb >> 4) ^ (row & 7u)) << 4) + (cb & 15u);
}

// async global->LDS, 16B per lane. LDS dest = wave-uniform base + lane*16 (linear).
__device__ __forceinline__ void gload16(const void* g, void* l) {
    __builtin_amdgcn_global_load_lds((const __attribute__((address_space(1))) void*)g,
                                     (__attribute__((address_space(3))) void*)l, 16, 0, 0);
}

// Pipeline LDS layout (3-deep, counted-vmcnt):
//  A bufs: ib*8192, ib in {0,1,2}  -> [0, 24576)
//  B bufs: 24576 + ib*32768        -> [24576, 122880)
// Each STAGE = 5 gload16 per wave (1 A + 4 B), split across the two phases.
// Phase schedule per K-iter (m201 port): P1 {ds_read a0..3,b0..3; issue A+B0;
// bar; lgkm0; sched_barrier; setprio1; MFMA nt0..3; setprio0; bar}; P2
// {ds_read b4..7; issue B1..3; bar; lgkm0; MFMA nt4..7; vmcnt(5); bar}.
// vmcnt(5) retires only batch t+1 (batch t+2 stays in flight) -- T4.

// Scratch map (row r = one of 32768 tokens):
//  src  slice r*2048B: [0,1024)=x_bf16 (xcvt; dead after outproj) -> h[1024:1536]
//                      [1024,2048)=x1 bf16 (outproj; read ff1, ff2-residual)
//  dout slice r*2048B: [0,1024)=k, [1024,2048)=v (qkv; dead after attn)
//                      -> h[0:1024] (ff1) -> final f32 out row (ff2, after h consumed)
//  ws: [0,6.3MB)=bf16 weights; [6.3,39.8MB) r*1024B: q (qkv) -> O (attn, same
//      block/cols) -> h[1536:2048] (ff1)
// Weight region layout (bf16 elems), ALL k-tile-major "LDS image" [tile][c][nn]:
//  unit u = 8 elems; within a region: tile=u>>11, c=(u>>9)&3, nn=u&511;
//  tile is 32KB = one K-step's B-panel; k = (tile%T_K)*32 + c*8, T_K = K/32.
//  Wqkv' [0,786432):        48 tiles; n=(tile>>4)*512+nn, k=(tile&15)*32+c*8
//  Wout' [786432,1048576):  16 tiles; n=nn, k=tile*32+c*8
//  W1'  [1048576,2097152): 128 tiles; n=(tile>>4)*512+nn, k=(tile&15)*32+c*8
//  W2'  [2097152,3145728):  64 tiles; n=nn, k=t*32+c*8

// ---------- weights f32 -> bf16, k-tile-major repack ----------
__global__ void wcvt_kernel(const float* __restrict__ wqkv, const float* __restrict__ wout,
                            const float* __restrict__ w1f, const float* __restrict__ w2f,
                            bf16* __restrict__ o) {
    int i = blockIdx.x * blockDim.x + threadIdx.x;  // one 8-elem unit
    const float* s;
    int soff, doff;
    if (i < 98304) {  // Wqkv: [1536][512] -> 48 tiles
        int u = i;
        int tile = u >> 11, c = (u >> 9) & 3, nn = u & 511;
        int n = (tile >> 4) * 512 + nn;
        int k = (tile & 15) * 32 + c * 8;
        s = wqkv; soff = n * 512 + k; doff = u * 8;
    } else if (i < 131072) {  // Wout: [512][512] -> 16 tiles
        int u = i - 98304;
        int tile = u >> 11, c = (u >> 9) & 3, nn = u & 511;
        int k = tile * 32 + c * 8;
        s = wout; soff = nn * 512 + k; doff = 786432 + u * 8;
    } else if (i < 262144) {  // W1: [2048][512] -> 128 tiles
        int u = i - 131072;
        int tile = u >> 11, c = (u >> 9) & 3, nn = u & 511;
        int n = (tile >> 4) * 512 + nn;
        int k = (tile & 15) * 32 + c * 8;
        s = w1f; soff = n * 512 + k; doff = 1048576 + u * 8;
    } else {  // W2: [512][2048] -> 64 tiles
        int u = i - 262144;
        int t = u >> 11, c = (u >> 9) & 3, nn = u & 511;
        int k = t * 32 + c * 8;
        s = w2f; soff = nn * 2048 + k; doff = 2097152 + u * 8;
    }
    float4 v0 = *(const float4*)(s + soff);
    float4 v1 = *(const float4*)(s + soff + 4);
    bf16x8 h = { (bf16)v0.x, (bf16)v0.y, (bf16)v0.z, (bf16)v0.w,
                 (bf16)v1.x, (bf16)v1.y, (bf16)v1.z, (bf16)v1.w };
    *(bf16x8*)(o + doff) = h;
}

// ---------- src f32 -> bf16 in place (row-aligned slot; wave per row) ----------
__global__ void xcvt_kernel(float* __restrict__ src) {
    int row = blockIdx.x * 4 + (threadIdx.x >> 6);
    int l = threadIdx.x & 63;
    float* rp = src + (size_t)row * 512 + l * 8;
    float4 v0 = *(const float4*)rp;
    float4 v1 = *(const float4*)(rp + 4);
    asm volatile("s_waitcnt vmcnt(0)" ::: "memory");  // all wave reads before any write
    bf16x8 h = { (bf16)v0.x, (bf16)v0.y, (bf16)v0.z, (bf16)v0.w,
                 (bf16)v1.x, (bf16)v1.y, (bf16)v1.z, (bf16)v1.w };
    *(bf16x8*)((bf16*)(src + (size_t)row * 512) + l * 8) = h;
}

// Shared phased main loop body. Requires macros STAGE_A(ib,t), STAGE_B(ib,t,j)
// and loop bound NT in scope; uses w/lane/l16/quad/wm/wn, smem, acc.
#define PHASED_LOOP(NT)                                                                \
    int ib = 0;                                                                        \
    _Pragma("unroll 1")                                                                \
    for (int t = 0; t < (NT); ++t) {                                                   \
        int in2 = ib + 2; if (in2 >= 3) in2 -= 3;                                      \
        const uint32_t A0 = (uint32_t)ib * 8192u;                                      \
        const uint32_t B0 = 24576u + (uint32_t)ib * 32768u;                            \
        bf16x8 a[4], b[8];                                                             \
        /* ---- Phase 1 ---- */                                                        \
        _Pragma("unroll")                                                              \
        for (int i = 0; i < 4; ++i)                                                    \
            a[i] = *(const bf16x8*)(smem + A0 + quad * 2048 + (wm * 64 + i * 16 + l16) * 16); \
        _Pragma("unroll")                                                              \
        for (int nt = 0; nt < 4; ++nt)                                                 \
            b[nt] = *(const bf16x8*)(smem + B0 + quad * 8192 + (wn * 128 + nt * 16 + l16) * 16); \
        if (t + 2 < (NT)) { STAGE_A(in2, t + 2); STAGE_B(in2, t + 2, 0); }             \
        __builtin_amdgcn_s_barrier();                                                  \
        asm volatile("s_waitcnt lgkmcnt(0)" ::: "memory");                             \
        __builtin_amdgcn_sched_barrier(0);                                             \
        __builtin_amdgcn_s_setprio(1);                                                 \
        _Pragma("unroll")                                                              \
        for (int nt = 0; nt < 4; ++nt)                                                 \
            _Pragma("unroll")                                                          \
            for (int i = 0; i < 4; ++i) acc[i][nt] = MFMA16(a[i], b[nt], acc[i][nt]);  \
        __builtin_amdgcn_s_setprio(0);                                                 \
        __builtin_amdgcn_s_barrier();                                                  \
        /* ---- Phase 2 ---- */                                                        \
        _Pragma("unroll")                                                              \
        for (int nt = 4; nt < 8; ++nt)                                                 \
            b[nt] = *(const bf16x8*)(smem + B0 + quad * 8192 + (wn * 128 + nt * 16 + l16) * 16); \
        if (t + 2 < (NT)) { STAGE_B(in2, t + 2, 1); STAGE_B(in2, t + 2, 2); STAGE_B(in2, t + 2, 3); } \
        __builtin_amdgcn_s_barrier();                                                  \
        asm volatile("s_waitcnt lgkmcnt(0)" ::: "memory");                             \
        __builtin_amdgcn_sched_barrier(0);                                             \
        __builtin_amdgcn_s_setprio(1);                                                 \
        _Pragma("unroll")                                                              \
        for (int nt = 4; nt < 8; ++nt)                                                 \
            _Pragma("unroll")                                                          \
            for (int i = 0; i < 4; ++i) acc[i][nt] = MFMA16(a[i], b[nt], acc[i][nt]);  \
        __builtin_amdgcn_s_setprio(0);                                                 \
        if (t + 2 < (NT)) asm volatile("s_waitcnt vmcnt(5)" ::: "memory");             \
        else              asm volatile("s_waitcnt vmcnt(0)" ::: "memory");             \
        __builtin_amdgcn_s_barrier();                                                  \
        ib = (ib == 2) ? 0 : ib + 1;                                                   \
    }

// ---------- qkv GEMM v4: M=32768 N=1536 K=512; 128x512 tile, grid (256,3) ----------
extern "C" __global__ __launch_bounds__(512, 2)
void qkv_kernel(const char* __restrict__ xb, const char* __restrict__ Wqkvp,
                const float* __restrict__ bqkv, char* __restrict__ qOb,
                char* __restrict__ kvb) {
    extern __shared__ char smem[];
    const int tid = threadIdx.x;
    const int w = tid >> 6, lane = tid & 63, l16 = lane & 15, quad = lane >> 4;
    const int wm = w >> 2, wn = w & 3;
    const int mb = blockIdx.x, cb = blockIdx.y;

    f32x4 acc[4][8];
#pragma unroll
    for (int i = 0; i < 4; ++i)
#pragma unroll
        for (int nt = 0; nt < 8; ++nt) acc[i][nt] = (f32x4){0.f, 0.f, 0.f, 0.f};

#define STAGE_A(ib_, t_)                                                               \
    {                                                                                  \
        int ca = w >> 1, rg = w & 1;                                                   \
        gload16(xb + (size_t)(mb * 128 + rg * 64 + lane) * 2048 + (t_) * 64 + ca * 16, \
                smem + (uint32_t)(ib_) * 8192u + ca * 2048 + rg * 1024);               \
    }
#define STAGE_B(ib_, t_, j_)                                                           \
    {                                                                                  \
        int idx = w * 4 + (j_), c = idx >> 3, ng = idx & 7;                            \
        gload16(Wqkvp + (size_t)(cb * 16 + (t_)) * 32768 + c * 8192 + ng * 1024 + lane * 16, \
                smem + 24576u + (uint32_t)(ib_) * 32768u + (uint32_t)c * 8192 + (uint32_t)ng * 1024); \
    }

    STAGE_A(0, 0); STAGE_B(0, 0, 0); STAGE_B(0, 0, 1); STAGE_B(0, 0, 2); STAGE_B(0, 0, 3);
    STAGE_A(1, 1); STAGE_B(1, 1, 0); STAGE_B(1, 1, 1); STAGE_B(1, 1, 2); STAGE_B(1, 1, 3);
    asm volatile("s_waitcnt vmcnt(5)" ::: "memory");
    __builtin_amdgcn_s_barrier();

    PHASED_LOOP(16)
#undef STAGE_A
#undef STAGE_B

    // epilogue: bias; per-i 16x128 transpose through 4KB wave scratch (dead B region)
    const uint32_t sb = 24576u + (uint32_t)w * 4096u;
#pragma unroll
    for (int i = 0; i < 4; ++i) {
#pragma unroll
        for (int nt = 0; nt < 8; ++nt) {
            float bb = bqkv[cb * 512 + wn * 128 + nt * 16 + l16];
#pragma unroll
            for (int r = 0; r < 4; ++r)
                *(bf16*)(smem + swz(sb, quad * 4 + r, 256, (nt * 16 + l16) * 2)) =
                    (bf16)(acc[i][nt][r] + bb);
        }
        asm volatile("s_waitcnt lgkmcnt(0)" ::: "memory");
#pragma unroll
        for (int j = 0; j < 4; ++j) {
            int uu = j * 64 + lane;  // 16 rows x 16 chunks
            int row = uu >> 4, ch = uu & 15;
            bf16x8 v = *(bf16x8*)(smem + swz(sb, row, 256, ch * 16));
            size_t row_g = (size_t)(mb * 128 + wm * 64 + i * 16 + row);
            int nb2 = wn * 256 + ch * 16;  // byte within this cb's 1024B col-slice
            if (cb == 0)      *(bf16x8*)(qOb + row_g * 1024 + nb2) = v;
            else if (cb == 1) *(bf16x8*)(kvb + row_g * 2048 + nb2) = v;
            else              *(bf16x8*)(kvb + row_g * 2048 + 1024 + nb2) = v;
        }
        asm volatile("s_waitcnt lgkmcnt(0)" ::: "memory");
    }
}

// ---------- attention: one block per (window, head) ----------
#define AVT 0u       // vT 64x128 bf16 rs=256B (16KB)
#define ASCR 16384u  // 8 waves x 2KB transpose scratch
extern "C" __global__ __launch_bounds__(512, 4)
void attn_kernel(char* __restrict__ qOb, const char* __restrict__ kvb) {
    extern __shared__ char smem[];
    const int tid = threadIdx.x;
    const int wid = tid >> 6, lane = tid & 63, l16 = lane & 15, quad = lane >> 4;
    const int win = blockIdx.x >> 3, head = blockIdx.x & 7;
    const size_t wrow0 = (size_t)win * 128;
    f32x4 zero4 = { 0.f, 0.f, 0.f, 0.f };

    // stage vT[dim][key] from v rows
    {
        int key = tid >> 2, d0 = (tid & 3) * 16;
        const char* vs = kvb + (wrow0 + key) * 2048 + 1024 + head * 128 + d0 * 2;
#pragma unroll
        for (int j = 0; j < 2; ++j) {
            bf16x8 v = *(const bf16x8*)(vs + j * 16);
#pragma unroll
            for (int e = 0; e < 8; ++e)
                *(bf16*)(smem + swz(AVT, d0 + j * 8 + e, 256, key * 2)) = v[e];
        }
    }
    __syncthreads();  // only barrier in this kernel

    // q fragments (A layout, direct from global)
    bf16x8 qf[2];
#pragma unroll
    for (int ks = 0; ks < 2; ++ks)
        qf[ks] = *(const bf16x8*)(qOb + (wrow0 + wid * 16 + l16) * 1024 + head * 128 + ks * 64 + quad * 16);

    // scores (k B-frags direct from global)
    f32x4 sa[8];
#pragma unroll
    for (int nt = 0; nt < 8; ++nt) sa[nt] = zero4;
#pragma unroll
    for (int nt = 0; nt < 8; ++nt)
#pragma unroll
        for (int ks = 0; ks < 2; ++ks) {
            bf16x8 kb = *(const bf16x8*)(kvb + (wrow0 + nt * 16 + l16) * 2048 + head * 128 + ks * 64 + quad * 16);
            sa[nt] = MFMA16(qf[ks], kb, sa[nt]);
        }
#pragma unroll
    for (int nt = 0; nt < 8; ++nt) sa[nt] *= 0.125f;
#pragma unroll
    for (int r = 0; r < 4; ++r) {
        float m = sa[0][r];
#pragma unroll
        for (int nt = 1; nt < 8; ++nt) m = fmaxf(m, sa[nt][r]);
#pragma unroll
        for (int sft = 1; sft < 16; sft <<= 1) m = fmaxf(m, __shfl_xor(m, sft, 64));
        float s = 0.f;
#pragma unroll
        for (int nt = 0; nt < 8; ++nt) {
            float e = __expf(sa[nt][r] - m);
            sa[nt][r] = e;
            s += e;
        }
#pragma unroll
        for (int sft = 1; sft < 16; sft <<= 1) s += __shfl_xor(s, sft, 64);
        float inv = 1.0f / s;
#pragma unroll
        for (int nt = 0; nt < 8; ++nt) sa[nt][r] *= inv;
    }

    // P C->A transpose through wave-private scratch
    const uint32_t sb = ASCR + (uint32_t)wid * 2048;
    bf16x8 pf[4];
#pragma unroll
    for (int hf = 0; hf < 2; ++hf) {
#pragma unroll
        for (int nt = 0; nt < 4; ++nt)
#pragma unroll
            for (int r = 0; r < 4; ++r)
                *(bf16*)(smem + swz(sb, quad * 4 + r, 128, (nt * 16 + l16) * 2)) = (bf16)sa[hf * 4 + nt][r];
        asm volatile("s_waitcnt lgkmcnt(0)" ::: "memory");
#pragma unroll
        for (int ks = 0; ks < 2; ++ks)
            pf[hf * 2 + ks] = *(bf16x8*)(smem + swz(sb, l16, 128, ks * 64 + quad * 16));
        asm volatile("s_waitcnt lgkmcnt(0)" ::: "memory");
    }

    // O = P @ V
    f32x4 ov[4];
#pragma unroll
    for (int nt = 0; nt < 4; ++nt) {
        ov[nt] = zero4;
#pragma unroll
        for (int ks = 0; ks < 4; ++ks) {
            bf16x8 vb = *(bf16x8*)(smem + swz(AVT, nt * 16 + l16, 256, ks * 64 + quad * 16));
            ov[nt] = MFMA16(pf[ks], vb, ov[nt]);
        }
    }
    // O store via transpose: two 32-col halves through 2KB wave scratch (rs=128)
#pragma unroll
    for (int hf = 0; hf < 2; ++hf) {
#pragma unroll
        for (int nt = 0; nt < 2; ++nt)
#pragma unroll
            for (int r = 0; r < 4; ++r)
                *(bf16*)(smem + swz(sb, quad * 4 + r, 128, (nt * 16 + l16) * 2)) = (bf16)ov[hf * 2 + nt][r];
        asm volatile("s_waitcnt lgkmcnt(0)" ::: "memory");
        {
            int row = lane >> 2, ch = lane & 3;
            bf16x8 v = *(bf16x8*)(smem + swz(sb, row, 128, ch * 16));
            *(bf16x8*)(qOb + (wrow0 + wid * 16 + row) * 1024 + head * 128 + hf * 64 + ch * 16) = v;
        }
        asm volatile("s_waitcnt lgkmcnt(0)" ::: "memory");
    }
}

// ---------- out-proj v4 + residual + LN1: M=32768 N=512 K=512 ----------
extern "C" __global__ __launch_bounds__(512, 2)
void outproj_kernel(char* __restrict__ srcb, const char* __restrict__ qOb,
                    const char* __restrict__ Woutp, const float* __restrict__ bout,
                    const float* __restrict__ g1, const float* __restrict__ be1) {
    extern __shared__ char smem[];
    const int tid = threadIdx.x;
    const int w = tid >> 6, lane = tid & 63, l16 = lane & 15, quad = lane >> 4;
    const int wm = w >> 2, wn = w & 3;
    const int mb = blockIdx.x;

    f32x4 acc[4][8];
#pragma unroll
    for (int i = 0; i < 4; ++i)
#pragma unroll
        for (int nt = 0; nt < 8; ++nt) acc[i][nt] = (f32x4){0.f, 0.f, 0.f, 0.f};

#define STAGE_A(ib_, t_)                                                               \
    {                                                                                  \
        int ca = w >> 1, rg = w & 1;                                                   \
        gload16(qOb + (size_t)(mb * 128 + rg * 64 + lane) * 1024 + (t_) * 64 + ca * 16, \
                smem + (uint32_t)(ib_) * 8192u + ca * 2048 + rg * 1024);               \
    }
#define STAGE_B(ib_, t_, j_)                                                           \
    {                                                                                  \
        int idx = w * 4 + (j_), c = idx >> 3, ng = idx & 7;                            \
        gload16(Woutp + (size_t)(t_) * 32768 + c * 8192 + ng * 1024 + lane * 16,       \
                smem + 24576u + (uint32_t)(ib_) * 32768u + (uint32_t)c * 8192 + (uint32_t)ng * 1024); \
    }

    STAGE_A(0, 0); STAGE_B(0, 0, 0); STAGE_B(0, 0, 1); STAGE_B(0, 0, 2); STAGE_B(0, 0, 3);
    STAGE_A(1, 1); STAGE_B(1, 1, 0); STAGE_B(1, 1, 1); STAGE_B(1, 1, 2); STAGE_B(1, 1, 3);
    asm volatile("s_waitcnt vmcnt(5)" ::: "memory");
    __builtin_amdgcn_s_barrier();

    PHASED_LOOP(16)
#undef STAGE_A
#undef STAGE_B

    // ---- bias + residual(x bf16) ----
#pragma unroll
    for (int nt = 0; nt < 8; ++nt) {
        int col = wn * 128 + nt * 16 + l16;
        float bb = bout[col];
#pragma unroll
        for (int i = 0; i < 4; ++i)
#pragma unroll
            for (int r = 0; r < 4; ++r) {
                int row = mb * 128 + wm * 64 + i * 16 + quad * 4 + r;
                float xv = (float)*(const bf16*)(srcb + (size_t)row * 2048 + col * 2);
                acc[i][nt][r] += bb + xv;
            }
    }
    // per-(row, wave) partials over this wave's 128 cols
    float ps[4][4], ps2[4][4];
#pragma unroll
    for (int i = 0; i < 4; ++i)
#pragma unroll
        for (int r = 0; r < 4; ++r) {
            float s = 0.f, s2 = 0.f;
#pragma unroll
            for (int nt = 0; nt < 8; ++nt) {
                float v = acc[i][nt][r];
                s += v;
                s2 += v * v;
            }
#pragma unroll
            for (int sft = 1; sft < 16; sft <<= 1) {
                s += __shfl_xor(s, sft, 64);
                s2 += __shfl_xor(s2, sft, 64);
            }
            ps[i][r] = s;
            ps2[i][r] = s2;
        }
    // cross-wave reduce via LDS scratch (dead A-buf): [128 rows][4 wn][2 f32]
    if (l16 == 0) {
#pragma unroll
        for (int i = 0; i < 4; ++i)
#pragma unroll
            for (int r = 0; r < 4; ++r) {
                int row_l = wm * 64 + i * 16 + quad * 4 + r;
                *(float*)(smem + row_l * 32 + wn * 8) = ps[i][r];
                *(float*)(smem + row_l * 32 + wn * 8 + 4) = ps2[i][r];
            }
    }
    __syncthreads();
    // per-i: LN1 + 16x128 transpose-store of bf16 x1 into srcb[1024:2048)
    const uint32_t sb = 24576u + (uint32_t)w * 4096u;  // dead B region
#pragma unroll
    for (int i = 0; i < 4; ++i) {
#pragma unroll
        for (int r = 0; r < 4; ++r) {
            int row_l = wm * 64 + i * 16 + quad * 4 + r;
            float S = 0.f, S2 = 0.f;
#pragma unroll
            for (int w4 = 0; w4 < 4; ++w4) {
                S += *(const float*)(smem + row_l * 32 + w4 * 8);
                S2 += *(const float*)(smem + row_l * 32 + w4 * 8 + 4);
            }
            float mu = S * (1.0f / 512.0f);
            float var = S2 * (1.0f / 512.0f) - mu * mu;
            float rstd = rsqrtf(var + 1e-5f);
#pragma unroll
            for (int nt = 0; nt < 8; ++nt) {
                int col = wn * 128 + nt * 16 + l16;
                float v = (acc[i][nt][r] - mu) * rstd * g1[col] + be1[col];
                *(bf16*)(smem + swz(sb, quad * 4 + r, 256, (nt * 16 + l16) * 2)) = (bf16)v;
            }
        }
        asm volatile("s_waitcnt lgkmcnt(0)" ::: "memory");
#pragma unroll
        for (int j = 0; j < 4; ++j) {
            int uu = j * 64 + lane;
            int row = uu >> 4, ch = uu & 15;
            bf16x8 v = *(bf16x8*)(smem + swz(sb, row, 256, ch * 16));
            *(bf16x8*)(srcb + (size_t)(mb * 128 + wm * 64 + i * 16 + row) * 2048 + 1024 +
                       wn * 256 + ch * 16) = v;
        }
        asm volatile("s_waitcnt lgkmcnt(0)" ::: "memory");
    }
}

// ---------- FF1 v5: M=32768 N=2048 K=512; 128x512 tile, grid (256,4) ----------
extern "C" __global__ __launch_bounds__(512, 2)
void ff1_kernel(char* __restrict__ srcb, const char* __restrict__ W1p,
                const float* __restrict__ b1, char* __restrict__ doutb,
                char* __restrict__ wsOb) {
    extern __shared__ char smem[];
    const int tid = threadIdx.x;
    const int w = tid >> 6, lane = tid & 63, l16 = lane & 15, quad = lane >> 4;
    const int wm = w >> 2, wn = w & 3;
    const int mb = blockIdx.x, cb = blockIdx.y;

    f32x4 acc[4][8];
#pragma unroll
    for (int i = 0; i < 4; ++i)
#pragma unroll
        for (int nt = 0; nt < 8; ++nt) acc[i][nt] = (f32x4){0.f, 0.f, 0.f, 0.f};

#define STAGE_A(ib_, t_)                                                               \
    {                                                                                  \
        int ca = w >> 1, rg = w & 1;                                                   \
        gload16(srcb + (size_t)(mb * 128 + rg * 64 + lane) * 2048 + 1024 + (t_) * 64 + ca * 16, \
                smem + (uint32_t)(ib_) * 8192u + ca * 2048 + rg * 1024);               \
    }
#define STAGE_B(ib_, t_, j_)                                                           \
    {                                                                                  \
        int idx = w * 4 + (j_), c = idx >> 3, ng = idx & 7;                            \
        gload16(W1p + (size_t)(cb * 16 + (t_)) * 32768 + c * 8192 + ng * 1024 + lane * 16, \
                smem + 24576u + (uint32_t)(ib_) * 32768u + (uint32_t)c * 8192 + (uint32_t)ng * 1024); \
    }

    STAGE_A(0, 0); STAGE_B(0, 0, 0); STAGE_B(0, 0, 1); STAGE_B(0, 0, 2); STAGE_B(0, 0, 3);
    STAGE_A(1, 1); STAGE_B(1, 1, 0); STAGE_B(1, 1, 1); STAGE_B(1, 1, 2); STAGE_B(1, 1, 3);
    asm volatile("s_waitcnt vmcnt(5)" ::: "memory");
    __builtin_amdgcn_s_barrier();

    PHASED_LOOP(16)
#undef STAGE_A
#undef STAGE_B

    // epilogue: bias+relu; per-i 16x128-col transpose through 4KB wave scratch
    const uint32_t sb = 24576u + (uint32_t)w * 4096u;  // dead B region
#pragma unroll
    for (int i = 0; i < 4; ++i) {
#pragma unroll
        for (int nt = 0; nt < 8; ++nt) {
            float bb = b1[cb * 512 + wn * 128 + nt * 16 + l16];
#pragma unroll
            for (int r = 0; r < 4; ++r)
                *(bf16*)(smem + swz(sb, quad * 4 + r, 256, (nt * 16 + l16) * 2)) =
                    (bf16)fmaxf(acc[i][nt][r] + bb, 0.0f);
        }
        asm volatile("s_waitcnt lgkmcnt(0)" ::: "memory");
#pragma unroll
        for (int j = 0; j < 4; ++j) {
            int uu = j * 64 + lane;  // 0..255: 16 rows x 16 chunks
            int row = uu >> 4, ch = uu & 15;
            bf16x8 v = *(bf16x8*)(smem + swz(sb, row, 256, ch * 16));
            size_t row_g = (size_t)(mb * 128 + wm * 64 + i * 16 + row);
            int nb2 = wn * 256 + ch * 16;  // byte within this cb's 1024B col-slice
            if (cb < 2)       *(bf16x8*)(doutb + row_g * 2048 + cb * 1024 + nb2) = v;
            else if (cb == 2) *(bf16x8*)(srcb + row_g * 2048 + nb2) = v;
            else              *(bf16x8*)(wsOb + row_g * 1024 + nb2) = v;
        }
        asm volatile("s_waitcnt lgkmcnt(0)" ::: "memory");
    }
}

// ---------- FF2 v7 + residual + LN2: M=32768 N=512 K=2048 -> f32 out ----------
extern "C" __global__ __launch_bounds__(512, 2)
void ff2_kernel(char* __restrict__ doutb, const char* __restrict__ srcb,
                const char* __restrict__ wsOb, const char* __restrict__ W2p,
                const float* __restrict__ b2, const float* __restrict__ g2,
                const float* __restrict__ be2) {
    extern __shared__ char smem[];
    const int tid = threadIdx.x;
    const int w = tid >> 6, lane = tid & 63, l16 = lane & 15, quad = lane >> 4;
    const int wm = w >> 2, wn = w & 3;
    const int mb = blockIdx.x;

    f32x4 acc[4][8];
#pragma unroll
    for (int i = 0; i < 4; ++i)
#pragma unroll
        for (int nt = 0; nt < 8; ++nt) acc[i][nt] = (f32x4){0.f, 0.f, 0.f, 0.f};

#define STAGE_A(ib_, t_)                                                               \
    {                                                                                  \
        const char* hb; int rstride, koffb;                                            \
        if ((t_) < 32)      { hb = doutb; rstride = 2048; koffb = (t_) * 64; }         \
        else if ((t_) < 48) { hb = srcb;  rstride = 2048; koffb = ((t_) - 32) * 64; }  \
        else                { hb = wsOb;  rstride = 1024; koffb = ((t_) - 48) * 64; }  \
        int ca = w >> 1, rg = w & 1;                                                   \
        gload16(hb + (size_t)(mb * 128 + rg * 64 + lane) * rstride + koffb + ca * 16,  \
                smem + (uint32_t)(ib_) * 8192u + ca * 2048 + rg * 1024);               \
    }
#define STAGE_B(ib_, t_, j_)                                                           \
    {                                                                                  \
        int idx = w * 4 + (j_), c = idx >> 3, ng = idx & 7;                            \
        gload16(W2p + (size_t)(t_) * 32768 + c * 8192 + ng * 1024 + lane * 16,         \
                smem + 24576u + (uint32_t)(ib_) * 32768u + (uint32_t)c * 8192 + (uint32_t)ng * 1024); \
    }

    STAGE_A(0, 0); STAGE_B(0, 0, 0); STAGE_B(0, 0, 1); STAGE_B(0, 0, 2); STAGE_B(0, 0, 3);
    STAGE_A(1, 1); STAGE_B(1, 1, 0); STAGE_B(1, 1, 1); STAGE_B(1, 1, 2); STAGE_B(1, 1, 3);
    asm volatile("s_waitcnt vmcnt(5)" ::: "memory");
    __builtin_amdgcn_s_barrier();

    PHASED_LOOP(64)
#undef STAGE_A
#undef STAGE_B

    // ---- epilogue: bias + residual(x1) + LN2 over full 512-col rows ----
#pragma unroll
    for (int nt = 0; nt < 8; ++nt) {
        int col = wn * 128 + nt * 16 + l16;
        float bb = b2[col];
#pragma unroll
        for (int i = 0; i < 4; ++i)
#pragma unroll
            for (int r = 0; r < 4; ++r) {
                int row = mb * 128 + wm * 64 + i * 16 + quad * 4 + r;
                float x1v = (float)*(const bf16*)(srcb + (size_t)row * 2048 + 1024 + col * 2);
                acc[i][nt][r] += bb + x1v;
            }
    }
    // per-(row, wave) partials over this wave's 128 cols
    float ps[4][4], ps2[4][4];
#pragma unroll
    for (int i = 0; i < 4; ++i)
#pragma unroll
        for (int r = 0; r < 4; ++r) {
            float s = 0.f, s2 = 0.f;
#pragma unroll
            for (int nt = 0; nt < 8; ++nt) {
                float v = acc[i][nt][r];
                s += v;
                s2 += v * v;
            }
#pragma unroll
            for (int sft = 1; sft < 16; sft <<= 1) {
                s += __shfl_xor(s, sft, 64);
                s2 += __shfl_xor(s2, sft, 64);
            }
            ps[i][r] = s;
            ps2[i][r] = s2;
        }
    // cross-wave reduce via LDS scratch (A-buf region dead): [128 rows][4 wn][2 f32]
    if (l16 == 0) {
#pragma unroll
        for (int i = 0; i < 4; ++i)
#pragma unroll
            for (int r = 0; r < 4; ++r) {
                int row_l = wm * 64 + i * 16 + quad * 4 + r;
                *(float*)(smem + row_l * 32 + wn * 8) = ps[i][r];
                *(float*)(smem + row_l * 32 + wn * 8 + 4) = ps2[i][r];
            }
    }
    __syncthreads();
#pragma unroll
    for (int i = 0; i < 4; ++i)
#pragma unroll
        for (int r = 0; r < 4; ++r) {
            int row_l = wm * 64 + i * 16 + quad * 4 + r;
            float S = 0.f, S2 = 0.f;
#pragma unroll
            for (int w4 = 0; w4 < 4; ++w4) {
                S += *(const float*)(smem + row_l * 32 + w4 * 8);
                S2 += *(const float*)(smem + row_l * 32 + w4 * 8 + 4);
            }
            float mu = S * (1.0f / 512.0f);
            float var = S2 * (1.0f / 512.0f) - mu * mu;
            float rstd = rsqrtf(var + 1e-5f);
            size_t row = (size_t)(mb * 128 + row_l);
#pragma unroll
            for (int nt = 0; nt < 8; ++nt) {
                int col = wn * 128 + nt * 16 + l16;
                *(float*)(doutb + row * 2048 + col * 4) =
                    (acc[i][nt][r] - mu) * rstd * g2[col] + be2[col];
            }
        }
}

extern "C" void kernel_launch(void* const* d_in, const int* in_sizes, int n_in,
                              void* d_out, int out_size, void* d_ws, size_t ws_size,
                              hipStream_t stream) {
    (void)in_sizes; (void)n_in; (void)out_size; (void)ws_size;
    float* src = (float*)d_in[0];
    const float* ipw = (const float*)d_in[1];
    const float* ipb = (const float*)d_in[2];
    const float* ow  = (const float*)d_in[3];
    const float* ob  = (const float*)d_in[4];
    const float* g1  = (const float*)d_in[5];
    const float* be1 = (const float*)d_in[6];
    const float* w1  = (const float*)d_in[7];
    const float* b1  = (const float*)d_in[8];
    const float* w2  = (const float*)d_in[9];
    const float* b2  = (const float*)d_in[10];
    const float* g2  = (const float*)d_in[11];
    const float* be2 = (const float*)d_in[12];
    bf16* ws = (bf16*)d_ws;
    char* srcb = (char*)src;
    char* doutb = (char*)d_out;
    char* qOb = (char*)d_ws + 6291456;  // 33.5 MB q/O/h-tail region

    wcvt_kernel<<<1536, 256, 0, stream>>>(ipw, ow, w1, w2, ws);
    xcvt_kernel<<<8192, 256, 0, stream>>>(src);

    hipFuncSetAttribute((const void*)qkv_kernel, hipFuncAttributeMaxDynamicSharedMemorySize, 122880);
    hipFuncSetAttribute((const void*)attn_kernel, hipFuncAttributeMaxDynamicSharedMemorySize, 32768);
    hipFuncSetAttribute((const void*)outproj_kernel, hipFuncAttributeMaxDynamicSharedMemorySize, 122880);
    hipFuncSetAttribute((const void*)ff1_kernel, hipFuncAttributeMaxDynamicSharedMemorySize, 122880);
    hipFuncSetAttribute((const void*)ff2_kernel, hipFuncAttributeMaxDynamicSharedMemorySize, 122880);

    qkv_kernel<<<dim3(256, 3), 512, 122880, stream>>>(srcb, (const char*)ws, ipb, qOb, doutb);
    attn_kernel<<<2048, 512, 32768, stream>>>(qOb, doutb);
    outproj_kernel<<<256, 512, 122880, stream>>>(srcb, qOb, (const char*)(ws + 786432), ob, g1, be1);
    ff1_kernel<<<dim3(256, 4), 512, 122880, stream>>>(srcb, (const char*)(ws + 1048576), b1, doutb, qOb);
    ff2_kernel<<<256, 512, 122880, stream>>>(doutb, srcb, qOb, (const char*)(ws + 2097152), b2, g2, be2);
}

// Round 7
// 490.079 us; speedup vs baseline: 1.0315x; 1.0315x over previous
//
#include <hip/hip_runtime.h>
#include <hip/hip_bf16.h>
#include <math.h>

typedef __bf16 bf16;
typedef bf16 bf16x8 __attribute__((ext_vector_type(8)));
typedef bf16 bf16x4 __attribute__((ext_vector_type(4)));
typedef float f32x4 __attribute__((ext_vector_type(4)));

#define MFMA16(a, b, c) __builtin_amdgcn_mfma_f32_16x16x32_bf16(a, b, c, 0, 0, 0)

// XOR-swizzle on 16B chunks within a row: breaks power-of-2 row-stride bank aliasing.
__device__ __forceinline__ uint32_t swz(uint32_t base, uint32_t row, uint32_t rs, uint32_t cb) {
    return base + row * rs + (((cb >> 4) ^ (row & 7u)) << 4) + (cb & 15u);
}

// async global->LDS, 16B per lane. LDS dest = wave-uniform base + lane*16 (linear).
__device__ __forceinline__ void gload16(const void* g, void* l) {
    __builtin_amdgcn_global_load_lds((const __attribute__((address_space(1))) void*)g,
                                     (__attribute__((address_space(3))) void*)l, 16, 0, 0);
}

// Two GEMM templates:
//  N512 (outproj/ff2, fused row-LN): 128x512 tile, 3-deep, phased (R5 schedule).
//    LDS: A ib*8192 [0,24576); B 24576+ib*32768 [24576,122880). 1 block/CU.
//  N256 (qkv/ff1): 128x256 tile, 3-deep counted vmcnt(3), single phase/iter,
//    16 MFMA/wave/iter. LDS: A ib*8192 [0,24576); B 24576+ib*16384 [24576,73728).
//    72KB -> 2 blocks/CU (4 waves/SIMD): cross-block TLP hides barrier drains.

// Scratch map (row r = one of 32768 tokens):
//  src  slice r*2048B: [0,1024)=x_bf16 (xcvt; dead after outproj) -> h[1024:1536]
//                      [1024,2048)=x1 bf16 (outproj; read ff1, ff2-residual)
//  dout slice r*2048B: [0,1024)=k, [1024,2048)=v (qkv; dead after attn)
//                      -> h[0:1024] (ff1) -> final f32 out row (ff2, after h consumed)
//  ws: [0,6.3MB)=bf16 weights; [6.3,39.8MB) r*1024B: q (qkv) -> O (attn, same
//      block/cols) -> h[1536:2048] (ff1)
// Weight regions (bf16 elems), k-tile-major "LDS image":
//  Wqkv' [0,786432):       96 tiles of 16KB (256 cols); unit u: tile=u>>10,
//      c=(u>>8)&3, nn=u&255; n=(tile>>4)*256+nn, k=(tile&15)*32+c*8
//  Wout' [786432,1048576): 16 tiles of 32KB (512 cols); u: tile=u>>11, c=(u>>9)&3,
//      nn=u&511; n=nn, k=tile*32+c*8
//  W1'  [1048576,2097152): 128 tiles of 16KB; n=(tile>>4)*256+nn, k=(tile&15)*32+c*8
//  W2'  [2097152,3145728): 64 tiles of 32KB; n=nn, k=tile*32+c*8

// ---------- weights f32 -> bf16, k-tile-major repack ----------
__global__ void wcvt_kernel(const float* __restrict__ wqkv, const float* __restrict__ wout,
                            const float* __restrict__ w1f, const float* __restrict__ w2f,
                            bf16* __restrict__ o) {
    int i = blockIdx.x * blockDim.x + threadIdx.x;  // one 8-elem unit
    const float* s;
    int soff, doff;
    if (i < 98304) {  // Wqkv: [1536][512] -> 96 16KB tiles
        int u = i;
        int tile = u >> 10, c = (u >> 8) & 3, nn = u & 255;
        int n = (tile >> 4) * 256 + nn;
        int k = (tile & 15) * 32 + c * 8;
        s = wqkv; soff = n * 512 + k; doff = u * 8;
    } else if (i < 131072) {  // Wout: [512][512] -> 16 32KB tiles
        int u = i - 98304;
        int tile = u >> 11, c = (u >> 9) & 3, nn = u & 511;
        int k = tile * 32 + c * 8;
        s = wout; soff = nn * 512 + k; doff = 786432 + u * 8;
    } else if (i < 262144) {  // W1: [2048][512] -> 128 16KB tiles
        int u = i - 131072;
        int tile = u >> 10, c = (u >> 8) & 3, nn = u & 255;
        int n = (tile >> 4) * 256 + nn;
        int k = (tile & 15) * 32 + c * 8;
        s = w1f; soff = n * 512 + k; doff = 1048576 + u * 8;
    } else {  // W2: [512][2048] -> 64 32KB tiles
        int u = i - 262144;
        int t = u >> 11, c = (u >> 9) & 3, nn = u & 511;
        int k = t * 32 + c * 8;
        s = w2f; soff = nn * 2048 + k; doff = 2097152 + u * 8;
    }
    float4 v0 = *(const float4*)(s + soff);
    float4 v1 = *(const float4*)(s + soff + 4);
    bf16x8 h = { (bf16)v0.x, (bf16)v0.y, (bf16)v0.z, (bf16)v0.w,
                 (bf16)v1.x, (bf16)v1.y, (bf16)v1.z, (bf16)v1.w };
    *(bf16x8*)(o + doff) = h;
}

// ---------- src f32 -> bf16 in place (row-aligned slot; wave per row) ----------
__global__ void xcvt_kernel(float* __restrict__ src) {
    int row = blockIdx.x * 4 + (threadIdx.x >> 6);
    int l = threadIdx.x & 63;
    float* rp = src + (size_t)row * 512 + l * 8;
    float4 v0 = *(const float4*)rp;
    float4 v1 = *(const float4*)(rp + 4);
    asm volatile("s_waitcnt vmcnt(0)" ::: "memory");  // all wave reads before any write
    bf16x8 h = { (bf16)v0.x, (bf16)v0.y, (bf16)v0.z, (bf16)v0.w,
                 (bf16)v1.x, (bf16)v1.y, (bf16)v1.z, (bf16)v1.w };
    *(bf16x8*)((bf16*)(src + (size_t)row * 512) + l * 8) = h;
}

// ---- N256 main loop: 3-deep, counted vmcnt(3), one phase/iter ----
// Needs STAGE_A(ib,t) (1 gload/wave) and STAGE_B2(ib,t,j) (j=0,1) in scope.
#define N256_LOOP(NT)                                                                  \
    int ib = 0;                                                                        \
    _Pragma("unroll 1")                                                                \
    for (int t = 0; t < (NT); ++t) {                                                   \
        int in2 = ib + 2; if (in2 >= 3) in2 -= 3;                                      \
        const uint32_t A0 = (uint32_t)ib * 8192u;                                      \
        const uint32_t B0 = 24576u + (uint32_t)ib * 16384u;                            \
        bf16x8 a[4], b[4];                                                             \
        _Pragma("unroll")                                                              \
        for (int i = 0; i < 4; ++i)                                                    \
            a[i] = *(const bf16x8*)(smem + A0 + quad * 2048 + (wm * 64 + i * 16 + l16) * 16); \
        _Pragma("unroll")                                                              \
        for (int nt = 0; nt < 4; ++nt)                                                 \
            b[nt] = *(const bf16x8*)(smem + B0 + quad * 4096 + (wn * 64 + nt * 16 + l16) * 16); \
        if (t + 2 < (NT)) { STAGE_A(in2, t + 2); STAGE_B2(in2, t + 2, 0); STAGE_B2(in2, t + 2, 1); } \
        _Pragma("unroll")                                                              \
        for (int nt = 0; nt < 4; ++nt)                                                 \
            _Pragma("unroll")                                                          \
            for (int i = 0; i < 4; ++i) acc[i][nt] = MFMA16(a[i], b[nt], acc[i][nt]);  \
        if (t + 2 < (NT)) asm volatile("s_waitcnt vmcnt(3)" ::: "memory");             \
        else              asm volatile("s_waitcnt vmcnt(0)" ::: "memory");             \
        __builtin_amdgcn_s_barrier();                                                  \
        ib = (ib == 2) ? 0 : ib + 1;                                                   \
    }

// ---- N512 phased main loop (R5 schedule, outproj/ff2) ----
#define PHASED_LOOP(NT)                                                                \
    int ib = 0;                                                                        \
    _Pragma("unroll 1")                                                                \
    for (int t = 0; t < (NT); ++t) {                                                   \
        int in2 = ib + 2; if (in2 >= 3) in2 -= 3;                                      \
        const uint32_t A0 = (uint32_t)ib * 8192u;                                      \
        const uint32_t B0 = 24576u + (uint32_t)ib * 32768u;                            \
        bf16x8 a[4], b[8];                                                             \
        /* ---- Phase 1 ---- */                                                        \
        _Pragma("unroll")                                                              \
        for (int i = 0; i < 4; ++i)                                                    \
            a[i] = *(const bf16x8*)(smem + A0 + quad * 2048 + (wm * 64 + i * 16 + l16) * 16); \
        _Pragma("unroll")                                                              \
        for (int nt = 0; nt < 4; ++nt)                                                 \
            b[nt] = *(const bf16x8*)(smem + B0 + quad * 8192 + (wn * 128 + nt * 16 + l16) * 16); \
        if (t + 2 < (NT)) { STAGE_A(in2, t + 2); STAGE_B(in2, t + 2, 0); }             \
        __builtin_amdgcn_s_barrier();                                                  \
        asm volatile("s_waitcnt lgkmcnt(0)" ::: "memory");                             \
        __builtin_amdgcn_sched_barrier(0);                                             \
        __builtin_amdgcn_s_setprio(1);                                                 \
        _Pragma("unroll")                                                              \
        for (int nt = 0; nt < 4; ++nt)                                                 \
            _Pragma("unroll")                                                          \
            for (int i = 0; i < 4; ++i) acc[i][nt] = MFMA16(a[i], b[nt], acc[i][nt]);  \
        __builtin_amdgcn_s_setprio(0);                                                 \
        __builtin_amdgcn_s_barrier();                                                  \
        /* ---- Phase 2 ---- */                                                        \
        _Pragma("unroll")                                                              \
        for (int nt = 4; nt < 8; ++nt)                                                 \
            b[nt] = *(const bf16x8*)(smem + B0 + quad * 8192 + (wn * 128 + nt * 16 + l16) * 16); \
        if (t + 2 < (NT)) { STAGE_B(in2, t + 2, 1); STAGE_B(in2, t + 2, 2); STAGE_B(in2, t + 2, 3); } \
        __builtin_amdgcn_s_barrier();                                                  \
        asm volatile("s_waitcnt lgkmcnt(0)" ::: "memory");                             \
        __builtin_amdgcn_sched_barrier(0);                                             \
        __builtin_amdgcn_s_setprio(1);                                                 \
        _Pragma("unroll")                                                              \
        for (int nt = 4; nt < 8; ++nt)                                                 \
            _Pragma("unroll")                                                          \
            for (int i = 0; i < 4; ++i) acc[i][nt] = MFMA16(a[i], b[nt], acc[i][nt]);  \
        __builtin_amdgcn_s_setprio(0);                                                 \
        if (t + 2 < (NT)) asm volatile("s_waitcnt vmcnt(5)" ::: "memory");             \
        else              asm volatile("s_waitcnt vmcnt(0)" ::: "memory");             \
        __builtin_amdgcn_s_barrier();                                                  \
        ib = (ib == 2) ? 0 : ib + 1;                                                   \
    }

// ---------- qkv GEMM v5: M=32768 N=1536 K=512; 128x256 tile, grid (256,6) ----------
extern "C" __global__ __launch_bounds__(512, 4)
void qkv_kernel(const char* __restrict__ xb, const char* __restrict__ Wqkvp,
                const float* __restrict__ bqkv, char* __restrict__ qOb,
                char* __restrict__ kvb) {
    extern __shared__ char smem[];
    const int tid = threadIdx.x;
    const int w = tid >> 6, lane = tid & 63, l16 = lane & 15, quad = lane >> 4;
    const int wm = w >> 2, wn = w & 3;
    const int mb = blockIdx.x, cb = blockIdx.y;

    f32x4 acc[4][4];
#pragma unroll
    for (int i = 0; i < 4; ++i)
#pragma unroll
        for (int nt = 0; nt < 4; ++nt) acc[i][nt] = (f32x4){0.f, 0.f, 0.f, 0.f};

#define STAGE_A(ib_, t_)                                                               \
    {                                                                                  \
        int ca = w >> 1, rg = w & 1;                                                   \
        gload16(xb + (size_t)(mb * 128 + rg * 64 + lane) * 2048 + (t_) * 64 + ca * 16, \
                smem + (uint32_t)(ib_) * 8192u + ca * 2048 + rg * 1024);               \
    }
#define STAGE_B2(ib_, t_, j_)                                                          \
    {                                                                                  \
        int idx = w * 2 + (j_), c = idx >> 2, ng = idx & 3;                            \
        gload16(Wqkvp + (size_t)(cb * 16 + (t_)) * 16384 + c * 4096 + ng * 1024 + lane * 16, \
                smem + 24576u + (uint32_t)(ib_) * 16384u + (uint32_t)c * 4096 + (uint32_t)ng * 1024); \
    }

    STAGE_A(0, 0); STAGE_B2(0, 0, 0); STAGE_B2(0, 0, 1);
    STAGE_A(1, 1); STAGE_B2(1, 1, 0); STAGE_B2(1, 1, 1);
    asm volatile("s_waitcnt vmcnt(3)" ::: "memory");
    __builtin_amdgcn_s_barrier();

    N256_LOOP(16)
#undef STAGE_A
#undef STAGE_B2

    // epilogue: bias; per-i 16x64 transpose through 2KB wave scratch (dead B region)
    const uint32_t sb = 24576u + (uint32_t)w * 2048u;
#pragma unroll
    for (int i = 0; i < 4; ++i) {
#pragma unroll
        for (int nt = 0; nt < 4; ++nt) {
            float bb = bqkv[cb * 256 + wn * 64 + nt * 16 + l16];
#pragma unroll
            for (int r = 0; r < 4; ++r)
                *(bf16*)(smem + swz(sb, quad * 4 + r, 128, (nt * 16 + l16) * 2)) =
                    (bf16)(acc[i][nt][r] + bb);
        }
        asm volatile("s_waitcnt lgkmcnt(0)" ::: "memory");
#pragma unroll
        for (int t2 = 0; t2 < 2; ++t2) {
            int row = t2 * 8 + (lane >> 3), ch = lane & 7;
            bf16x8 v = *(bf16x8*)(smem + swz(sb, row, 128, ch * 16));
            size_t row_g = (size_t)(mb * 128 + wm * 64 + i * 16 + row);
            int cbyte = wn * 128 + ch * 16;  // within this cb's 512B col-slice
            if (cb < 2)      *(bf16x8*)(qOb + row_g * 1024 + cb * 512 + cbyte) = v;
            else if (cb < 4) *(bf16x8*)(kvb + row_g * 2048 + (cb - 2) * 512 + cbyte) = v;
            else             *(bf16x8*)(kvb + row_g * 2048 + 1024 + (cb - 4) * 512 + cbyte) = v;
        }
        asm volatile("s_waitcnt lgkmcnt(0)" ::: "memory");
    }
}

// ---------- attention: one block per (window, head) ----------
#define AVT 0u       // vT 64x128 bf16 rs=256B (16KB)
#define ASCR 16384u  // 8 waves x 2KB transpose scratch
extern "C" __global__ __launch_bounds__(512, 4)
void attn_kernel(char* __restrict__ qOb, const char* __restrict__ kvb) {
    extern __shared__ char smem[];
    const int tid = threadIdx.x;
    const int wid = tid >> 6, lane = tid & 63, l16 = lane & 15, quad = lane >> 4;
    const int win = blockIdx.x >> 3, head = blockIdx.x & 7;
    const size_t wrow0 = (size_t)win * 128;
    f32x4 zero4 = { 0.f, 0.f, 0.f, 0.f };

    // stage vT[dim][key] from v rows
    {
        int key = tid >> 2, d0 = (tid & 3) * 16;
        const char* vs = kvb + (wrow0 + key) * 2048 + 1024 + head * 128 + d0 * 2;
#pragma unroll
        for (int j = 0; j < 2; ++j) {
            bf16x8 v = *(const bf16x8*)(vs + j * 16);
#pragma unroll
            for (int e = 0; e < 8; ++e)
                *(bf16*)(smem + swz(AVT, d0 + j * 8 + e, 256, key * 2)) = v[e];
        }
    }
    __syncthreads();  // only barrier in this kernel

    // q fragments (A layout, direct from global)
    bf16x8 qf[2];
#pragma unroll
    for (int ks = 0; ks < 2; ++ks)
        qf[ks] = *(const bf16x8*)(qOb + (wrow0 + wid * 16 + l16) * 1024 + head * 128 + ks * 64 + quad * 16);

    // scores (k B-frags direct from global)
    f32x4 sa[8];
#pragma unroll
    for (int nt = 0; nt < 8; ++nt) sa[nt] = zero4;
#pragma unroll
    for (int nt = 0; nt < 8; ++nt)
#pragma unroll
        for (int ks = 0; ks < 2; ++ks) {
            bf16x8 kb = *(const bf16x8*)(kvb + (wrow0 + nt * 16 + l16) * 2048 + head * 128 + ks * 64 + quad * 16);
            sa[nt] = MFMA16(qf[ks], kb, sa[nt]);
        }
#pragma unroll
    for (int nt = 0; nt < 8; ++nt) sa[nt] *= 0.125f;
#pragma unroll
    for (int r = 0; r < 4; ++r) {
        float m = sa[0][r];
#pragma unroll
        for (int nt = 1; nt < 8; ++nt) m = fmaxf(m, sa[nt][r]);
#pragma unroll
        for (int sft = 1; sft < 16; sft <<= 1) m = fmaxf(m, __shfl_xor(m, sft, 64));
        float s = 0.f;
#pragma unroll
        for (int nt = 0; nt < 8; ++nt) {
            float e = __expf(sa[nt][r] - m);
            sa[nt][r] = e;
            s += e;
        }
#pragma unroll
        for (int sft = 1; sft < 16; sft <<= 1) s += __shfl_xor(s, sft, 64);
        float inv = 1.0f / s;
#pragma unroll
        for (int nt = 0; nt < 8; ++nt) sa[nt][r] *= inv;
    }

    // P C->A transpose through wave-private scratch
    const uint32_t sb = ASCR + (uint32_t)wid * 2048;
    bf16x8 pf[4];
#pragma unroll
    for (int hf = 0; hf < 2; ++hf) {
#pragma unroll
        for (int nt = 0; nt < 4; ++nt)
#pragma unroll
            for (int r = 0; r < 4; ++r)
                *(bf16*)(smem + swz(sb, quad * 4 + r, 128, (nt * 16 + l16) * 2)) = (bf16)sa[hf * 4 + nt][r];
        asm volatile("s_waitcnt lgkmcnt(0)" ::: "memory");
#pragma unroll
        for (int ks = 0; ks < 2; ++ks)
            pf[hf * 2 + ks] = *(bf16x8*)(smem + swz(sb, l16, 128, ks * 64 + quad * 16));
        asm volatile("s_waitcnt lgkmcnt(0)" ::: "memory");
    }

    // O = P @ V
    f32x4 ov[4];
#pragma unroll
    for (int nt = 0; nt < 4; ++nt) {
        ov[nt] = zero4;
#pragma unroll
        for (int ks = 0; ks < 4; ++ks) {
            bf16x8 vb = *(bf16x8*)(smem + swz(AVT, nt * 16 + l16, 256, ks * 64 + quad * 16));
            ov[nt] = MFMA16(pf[ks], vb, ov[nt]);
        }
    }
    // O store via transpose: two 32-col halves through 2KB wave scratch (rs=128)
#pragma unroll
    for (int hf = 0; hf < 2; ++hf) {
#pragma unroll
        for (int nt = 0; nt < 2; ++nt)
#pragma unroll
            for (int r = 0; r < 4; ++r)
                *(bf16*)(smem + swz(sb, quad * 4 + r, 128, (nt * 16 + l16) * 2)) = (bf16)ov[hf * 2 + nt][r];
        asm volatile("s_waitcnt lgkmcnt(0)" ::: "memory");
        {
            int row = lane >> 2, ch = lane & 3;
            bf16x8 v = *(bf16x8*)(smem + swz(sb, row, 128, ch * 16));
            *(bf16x8*)(qOb + (wrow0 + wid * 16 + row) * 1024 + head * 128 + hf * 64 + ch * 16) = v;
        }
        asm volatile("s_waitcnt lgkmcnt(0)" ::: "memory");
    }
}

// ---------- out-proj v4 + residual + LN1: M=32768 N=512 K=512 ----------
extern "C" __global__ __launch_bounds__(512, 2)
void outproj_kernel(char* __restrict__ srcb, const char* __restrict__ qOb,
                    const char* __restrict__ Woutp, const float* __restrict__ bout,
                    const float* __restrict__ g1, const float* __restrict__ be1) {
    extern __shared__ char smem[];
    const int tid = threadIdx.x;
    const int w = tid >> 6, lane = tid & 63, l16 = lane & 15, quad = lane >> 4;
    const int wm = w >> 2, wn = w & 3;
    const int mb = blockIdx.x;

    f32x4 acc[4][8];
#pragma unroll
    for (int i = 0; i < 4; ++i)
#pragma unroll
        for (int nt = 0; nt < 8; ++nt) acc[i][nt] = (f32x4){0.f, 0.f, 0.f, 0.f};

#define STAGE_A(ib_, t_)                                                               \
    {                                                                                  \
        int ca = w >> 1, rg = w & 1;                                                   \
        gload16(qOb + (size_t)(mb * 128 + rg * 64 + lane) * 1024 + (t_) * 64 + ca * 16, \
                smem + (uint32_t)(ib_) * 8192u + ca * 2048 + rg * 1024);               \
    }
#define STAGE_B(ib_, t_, j_)                                                           \
    {                                                                                  \
        int idx = w * 4 + (j_), c = idx >> 3, ng = idx & 7;                            \
        gload16(Woutp + (size_t)(t_) * 32768 + c * 8192 + ng * 1024 + lane * 16,       \
                smem + 24576u + (uint32_t)(ib_) * 32768u + (uint32_t)c * 8192 + (uint32_t)ng * 1024); \
    }

    STAGE_A(0, 0); STAGE_B(0, 0, 0); STAGE_B(0, 0, 1); STAGE_B(0, 0, 2); STAGE_B(0, 0, 3);
    STAGE_A(1, 1); STAGE_B(1, 1, 0); STAGE_B(1, 1, 1); STAGE_B(1, 1, 2); STAGE_B(1, 1, 3);
    asm volatile("s_waitcnt vmcnt(5)" ::: "memory");
    __builtin_amdgcn_s_barrier();

    PHASED_LOOP(16)
#undef STAGE_A
#undef STAGE_B

    // ---- bias + residual(x bf16) ----
#pragma unroll
    for (int nt = 0; nt < 8; ++nt) {
        int col = wn * 128 + nt * 16 + l16;
        float bb = bout[col];
#pragma unroll
        for (int i = 0; i < 4; ++i)
#pragma unroll
            for (int r = 0; r < 4; ++r) {
                int row = mb * 128 + wm * 64 + i * 16 + quad * 4 + r;
                float xv = (float)*(const bf16*)(srcb + (size_t)row * 2048 + col * 2);
                acc[i][nt][r] += bb + xv;
            }
    }
    // per-(row, wave) partials over this wave's 128 cols
    float ps[4][4], ps2[4][4];
#pragma unroll
    for (int i = 0; i < 4; ++i)
#pragma unroll
        for (int r = 0; r < 4; ++r) {
            float s = 0.f, s2 = 0.f;
#pragma unroll
            for (int nt = 0; nt < 8; ++nt) {
                float v = acc[i][nt][r];
                s += v;
                s2 += v * v;
            }
#pragma unroll
            for (int sft = 1; sft < 16; sft <<= 1) {
                s += __shfl_xor(s, sft, 64);
                s2 += __shfl_xor(s2, sft, 64);
            }
            ps[i][r] = s;
            ps2[i][r] = s2;
        }
    // cross-wave reduce via LDS scratch (dead A-buf): [128 rows][4 wn][2 f32]
    if (l16 == 0) {
#pragma unroll
        for (int i = 0; i < 4; ++i)
#pragma unroll
            for (int r = 0; r < 4; ++r) {
                int row_l = wm * 64 + i * 16 + quad * 4 + r;
                *(float*)(smem + row_l * 32 + wn * 8) = ps[i][r];
                *(float*)(smem + row_l * 32 + wn * 8 + 4) = ps2[i][r];
            }
    }
    __syncthreads();
    // per-i: LN1 + 16x128 transpose-store of bf16 x1 into srcb[1024:2048)
    const uint32_t sb = 24576u + (uint32_t)w * 4096u;  // dead B region
#pragma unroll
    for (int i = 0; i < 4; ++i) {
#pragma unroll
        for (int r = 0; r < 4; ++r) {
            int row_l = wm * 64 + i * 16 + quad * 4 + r;
            float S = 0.f, S2 = 0.f;
#pragma unroll
            for (int w4 = 0; w4 < 4; ++w4) {
                S += *(const float*)(smem + row_l * 32 + w4 * 8);
                S2 += *(const float*)(smem + row_l * 32 + w4 * 8 + 4);
            }
            float mu = S * (1.0f / 512.0f);
            float var = S2 * (1.0f / 512.0f) - mu * mu;
            float rstd = rsqrtf(var + 1e-5f);
#pragma unroll
            for (int nt = 0; nt < 8; ++nt) {
                int col = wn * 128 + nt * 16 + l16;
                float v = (acc[i][nt][r] - mu) * rstd * g1[col] + be1[col];
                *(bf16*)(smem + swz(sb, quad * 4 + r, 256, (nt * 16 + l16) * 2)) = (bf16)v;
            }
        }
        asm volatile("s_waitcnt lgkmcnt(0)" ::: "memory");
#pragma unroll
        for (int j = 0; j < 4; ++j) {
            int uu = j * 64 + lane;
            int row = uu >> 4, ch = uu & 15;
            bf16x8 v = *(bf16x8*)(smem + swz(sb, row, 256, ch * 16));
            *(bf16x8*)(srcb + (size_t)(mb * 128 + wm * 64 + i * 16 + row) * 2048 + 1024 +
                       wn * 256 + ch * 16) = v;
        }
        asm volatile("s_waitcnt lgkmcnt(0)" ::: "memory");
    }
}

// ---------- FF1 v6: M=32768 N=2048 K=512; 128x256 tile, grid (256,8) ----------
extern "C" __global__ __launch_bounds__(512, 4)
void ff1_kernel(char* __restrict__ srcb, const char* __restrict__ W1p,
                const float* __restrict__ b1, char* __restrict__ doutb,
                char* __restrict__ wsOb) {
    extern __shared__ char smem[];
    const int tid = threadIdx.x;
    const int w = tid >> 6, lane = tid & 63, l16 = lane & 15, quad = lane >> 4;
    const int wm = w >> 2, wn = w & 3;
    const int mb = blockIdx.x, cb = blockIdx.y;

    f32x4 acc[4][4];
#pragma unroll
    for (int i = 0; i < 4; ++i)
#pragma unroll
        for (int nt = 0; nt < 4; ++nt) acc[i][nt] = (f32x4){0.f, 0.f, 0.f, 0.f};

#define STAGE_A(ib_, t_)                                                               \
    {                                                                                  \
        int ca = w >> 1, rg = w & 1;                                                   \
        gload16(srcb + (size_t)(mb * 128 + rg * 64 + lane) * 2048 + 1024 + (t_) * 64 + ca * 16, \
                smem + (uint32_t)(ib_) * 8192u + ca * 2048 + rg * 1024);               \
    }
#define STAGE_B2(ib_, t_, j_)                                                          \
    {                                                                                  \
        int idx = w * 2 + (j_), c = idx >> 2, ng = idx & 3;                            \
        gload16(W1p + (size_t)(cb * 16 + (t_)) * 16384 + c * 4096 + ng * 1024 + lane * 16, \
                smem + 24576u + (uint32_t)(ib_) * 16384u + (uint32_t)c * 4096 + (uint32_t)ng * 1024); \
    }

    STAGE_A(0, 0); STAGE_B2(0, 0, 0); STAGE_B2(0, 0, 1);
    STAGE_A(1, 1); STAGE_B2(1, 1, 0); STAGE_B2(1, 1, 1);
    asm volatile("s_waitcnt vmcnt(3)" ::: "memory");
    __builtin_amdgcn_s_barrier();

    N256_LOOP(16)
#undef STAGE_A
#undef STAGE_B2

    // epilogue: bias+relu; per-i 16x64 transpose through 2KB wave scratch
    const uint32_t sb = 24576u + (uint32_t)w * 2048u;
#pragma unroll
    for (int i = 0; i < 4; ++i) {
#pragma unroll
        for (int nt = 0; nt < 4; ++nt) {
            float bb = b1[cb * 256 + wn * 64 + nt * 16 + l16];
#pragma unroll
            for (int r = 0; r < 4; ++r)
                *(bf16*)(smem + swz(sb, quad * 4 + r, 128, (nt * 16 + l16) * 2)) =
                    (bf16)fmaxf(acc[i][nt][r] + bb, 0.0f);
        }
        asm volatile("s_waitcnt lgkmcnt(0)" ::: "memory");
#pragma unroll
        for (int t2 = 0; t2 < 2; ++t2) {
            int row = t2 * 8 + (lane >> 3), ch = lane & 7;
            bf16x8 v = *(bf16x8*)(smem + swz(sb, row, 128, ch * 16));
            size_t row_g = (size_t)(mb * 128 + wm * 64 + i * 16 + row);
            int cbyte = wn * 128 + ch * 16;  // within this cb's 512B col-slice
            if (cb < 4)      *(bf16x8*)(doutb + row_g * 2048 + cb * 512 + cbyte) = v;
            else if (cb < 6) *(bf16x8*)(srcb + row_g * 2048 + (cb - 4) * 512 + cbyte) = v;
            else             *(bf16x8*)(wsOb + row_g * 1024 + (cb - 6) * 512 + cbyte) = v;
        }
        asm volatile("s_waitcnt lgkmcnt(0)" ::: "memory");
    }
}

// ---------- FF2 v7 + residual + LN2: M=32768 N=512 K=2048 -> f32 out ----------
extern "C" __global__ __launch_bounds__(512, 2)
void ff2_kernel(char* __restrict__ doutb, const char* __restrict__ srcb,
                const char* __restrict__ wsOb, const char* __restrict__ W2p,
                const float* __restrict__ b2, const float* __restrict__ g2,
                const float* __restrict__ be2) {
    extern __shared__ char smem[];
    const int tid = threadIdx.x;
    const int w = tid >> 6, lane = tid & 63, l16 = lane & 15, quad = lane >> 4;
    const int wm = w >> 2, wn = w & 3;
    const int mb = blockIdx.x;

    f32x4 acc[4][8];
#pragma unroll
    for (int i = 0; i < 4; ++i)
#pragma unroll
        for (int nt = 0; nt < 8; ++nt) acc[i][nt] = (f32x4){0.f, 0.f, 0.f, 0.f};

#define STAGE_A(ib_, t_)                                                               \
    {                                                                                  \
        const char* hb; int rstride, koffb;                                            \
        if ((t_) < 32)      { hb = doutb; rstride = 2048; koffb = (t_) * 64; }         \
        else if ((t_) < 48) { hb = srcb;  rstride = 2048; koffb = ((t_) - 32) * 64; }  \
        else                { hb = wsOb;  rstride = 1024; koffb = ((t_) - 48) * 64; }  \
        int ca = w >> 1, rg = w & 1;                                                   \
        gload16(hb + (size_t)(mb * 128 + rg * 64 + lane) * rstride + koffb + ca * 16,  \
                smem + (uint32_t)(ib_) * 8192u + ca * 2048 + rg * 1024);               \
    }
#define STAGE_B(ib_, t_, j_)                                                           \
    {                                                                                  \
        int idx = w * 4 + (j_), c = idx >> 3, ng = idx & 7;                            \
        gload16(W2p + (size_t)(t_) * 32768 + c * 8192 + ng * 1024 + lane * 16,         \
                smem + 24576u + (uint32_t)(ib_) * 32768u + (uint32_t)c * 8192 + (uint32_t)ng * 1024); \
    }

    STAGE_A(0, 0); STAGE_B(0, 0, 0); STAGE_B(0, 0, 1); STAGE_B(0, 0, 2); STAGE_B(0, 0, 3);
    STAGE_A(1, 1); STAGE_B(1, 1, 0); STAGE_B(1, 1, 1); STAGE_B(1, 1, 2); STAGE_B(1, 1, 3);
    asm volatile("s_waitcnt vmcnt(5)" ::: "memory");
    __builtin_amdgcn_s_barrier();

    PHASED_LOOP(64)
#undef STAGE_A
#undef STAGE_B

    // ---- epilogue: bias + residual(x1) + LN2 over full 512-col rows ----
#pragma unroll
    for (int nt = 0; nt < 8; ++nt) {
        int col = wn * 128 + nt * 16 + l16;
        float bb = b2[col];
#pragma unroll
        for (int i = 0; i < 4; ++i)
#pragma unroll
            for (int r = 0; r < 4; ++r) {
                int row = mb * 128 + wm * 64 + i * 16 + quad * 4 + r;
                float x1v = (float)*(const bf16*)(srcb + (size_t)row * 2048 + 1024 + col * 2);
                acc[i][nt][r] += bb + x1v;
            }
    }
    // per-(row, wave) partials over this wave's 128 cols
    float ps[4][4], ps2[4][4];
#pragma unroll
    for (int i = 0; i < 4; ++i)
#pragma unroll
        for (int r = 0; r < 4; ++r) {
            float s = 0.f, s2 = 0.f;
#pragma unroll
            for (int nt = 0; nt < 8; ++nt) {
                float v = acc[i][nt][r];
                s += v;
                s2 += v * v;
            }
#pragma unroll
            for (int sft = 1; sft < 16; sft <<= 1) {
                s += __shfl_xor(s, sft, 64);
                s2 += __shfl_xor(s2, sft, 64);
            }
            ps[i][r] = s;
            ps2[i][r] = s2;
        }
    // cross-wave reduce via LDS scratch (A-buf region dead): [128 rows][4 wn][2 f32]
    if (l16 == 0) {
#pragma unroll
        for (int i = 0; i < 4; ++i)
#pragma unroll
            for (int r = 0; r < 4; ++r) {
                int row_l = wm * 64 + i * 16 + quad * 4 + r;
                *(float*)(smem + row_l * 32 + wn * 8) = ps[i][r];
                *(float*)(smem + row_l * 32 + wn * 8 + 4) = ps2[i][r];
            }
    }
    __syncthreads();
#pragma unroll
    for (int i = 0; i < 4; ++i)
#pragma unroll
        for (int r = 0; r < 4; ++r) {
            int row_l = wm * 64 + i * 16 + quad * 4 + r;
            float S = 0.f, S2 = 0.f;
#pragma unroll
            for (int w4 = 0; w4 < 4; ++w4) {
                S += *(const float*)(smem + row_l * 32 + w4 * 8);
                S2 += *(const float*)(smem + row_l * 32 + w4 * 8 + 4);
            }
            float mu = S * (1.0f / 512.0f);
            float var = S2 * (1.0f / 512.0f) - mu * mu;
            float rstd = rsqrtf(var + 1e-5f);
            size_t row = (size_t)(mb * 128 + row_l);
#pragma unroll
            for (int nt = 0; nt < 8; ++nt) {
                int col = wn * 128 + nt * 16 + l16;
                *(float*)(doutb + row * 2048 + col * 4) =
                    (acc[i][nt][r] - mu) * rstd * g2[col] + be2[col];
            }
        }
}

extern "C" void kernel_launch(void* const* d_in, const int* in_sizes, int n_in,
                              void* d_out, int out_size, void* d_ws, size_t ws_size,
                              hipStream_t stream) {
    (void)in_sizes; (void)n_in; (void)out_size; (void)ws_size;
    float* src = (float*)d_in[0];
    const float* ipw = (const float*)d_in[1];
    const float* ipb = (const float*)d_in[2];
    const float* ow  = (const float*)d_in[3];
    const float* ob  = (const float*)d_in[4];
    const float* g1  = (const float*)d_in[5];
    const float* be1 = (const float*)d_in[6];
    const float* w1  = (const float*)d_in[7];
    const float* b1  = (const float*)d_in[8];
    const float* w2  = (const float*)d_in[9];
    const float* b2  = (const float*)d_in[10];
    const float* g2  = (const float*)d_in[11];
    const float* be2 = (const float*)d_in[12];
    bf16* ws = (bf16*)d_ws;
    char* srcb = (char*)src;
    char* doutb = (char*)d_out;
    char* qOb = (char*)d_ws + 6291456;  // 33.5 MB q/O/h-tail region

    wcvt_kernel<<<1536, 256, 0, stream>>>(ipw, ow, w1, w2, ws);
    xcvt_kernel<<<8192, 256, 0, stream>>>(src);

    hipFuncSetAttribute((const void*)qkv_kernel, hipFuncAttributeMaxDynamicSharedMemorySize, 73728);
    hipFuncSetAttribute((const void*)attn_kernel, hipFuncAttributeMaxDynamicSharedMemorySize, 32768);
    hipFuncSetAttribute((const void*)outproj_kernel, hipFuncAttributeMaxDynamicSharedMemorySize, 122880);
    hipFuncSetAttribute((const void*)ff1_kernel, hipFuncAttributeMaxDynamicSharedMemorySize, 73728);
    hipFuncSetAttribute((const void*)ff2_kernel, hipFuncAttributeMaxDynamicSharedMemorySize, 122880);

    qkv_kernel<<<dim3(256, 6), 512, 73728, stream>>>(srcb, (const char*)ws, ipb, qOb, doutb);
    attn_kernel<<<2048, 512, 32768, stream>>>(qOb, doutb);
    outproj_kernel<<<256, 512, 122880, stream>>>(srcb, qOb, (const char*)(ws + 786432), ob, g1, be1);
    ff1_kernel<<<dim3(256, 8), 512, 73728, stream>>>(srcb, (const char*)(ws + 1048576), b1, doutb, qOb);
    ff2_kernel<<<256, 512, 122880, stream>>>(doutb, srcb, qOb, (const char*)(ws + 2097152), b2, g2, be2);
}

// Round 8
// 488.609 us; speedup vs baseline: 1.0347x; 1.0030x over previous
//
#include <hip/hip_runtime.h>
#include <hip/hip_bf16.h>
#include <math.h>

typedef __bf16 bf16;
typedef bf16 bf16x8 __attribute__((ext_vector_type(8)));
typedef bf16 bf16x4 __attribute__((ext_vector_type(4)));
typedef float f32x4 __attribute__((ext_vector_type(4)));

#define MFMA16(a, b, c) __builtin_amdgcn_mfma_f32_16x16x32_bf16(a, b, c, 0, 0, 0)

// XOR-swizzle on 16B chunks within a row: breaks power-of-2 row-stride bank aliasing.
__device__ __forceinline__ uint32_t swz(uint32_t base, uint32_t row, uint32_t rs, uint32_t cb) {
    return base + row * rs + (((cb >> 4) ^ (row & 7u)) << 4) + (cb & 15u);
}

// async global->LDS, 16B per lane. LDS dest = wave-uniform base + lane*16 (linear).
__device__ __forceinline__ void gload16(const void* g, void* l) {
    __builtin_amdgcn_global_load_lds((const __attribute__((address_space(1))) void*)g,
                                     (__attribute__((address_space(3))) void*)l, 16, 0, 0);
}

// Two GEMM templates:
//  N512 (outproj, fused row-LN1): 128x512 tile, 3-deep, phased (R5 schedule).
//    LDS: A ib*8192 [0,24576); B 24576+ib*32768 [24576,122880). 1 block/CU.
//  N256 (qkv/ff1/ff2): 128x256 tile, 3-deep counted vmcnt(3), single phase/iter,
//    16 MFMA/wave/iter. LDS: A ib*8192 [0,24576); B 24576+ib*16384 [24576,73728).
//    72KB -> 2 blocks/CU (4 waves/SIMD): cross-block TLP hides barrier drains.
//  ff2's LN2 is DE-FUSED: ff2 writes y=GEMM+bias+residual f32; ln2_kernel
//  (wave per row) normalizes in place. ~20us extra, unlocks 2-block template.

// Scratch map (row r = one of 32768 tokens):
//  src  slice r*2048B: [0,1024)=x_bf16 (xcvt; dead after outproj) -> h[1024:1536]
//                      [1024,2048)=x1 bf16 (outproj; read ff1, ff2-residual)
//  dout slice r*2048B: [0,1024)=k, [1024,2048)=v (qkv; dead after attn)
//                      -> h[0:1024] (ff1) -> y/out f32 row (ff2 epilogue, after
//                        that block's h reads done; ln2 normalizes in place)
//  ws: [0,6.3MB)=bf16 weights; [6.3,39.8MB) r*1024B: q (qkv) -> O (attn, same
//      block/cols) -> h[1536:2048] (ff1)
// Weight regions (bf16 elems), k-tile-major "LDS image":
//  Wqkv' [0,786432):       96 tiles of 16KB (256 cols); unit u: tile=u>>10,
//      c=(u>>8)&3, nn=u&255; n=(tile>>4)*256+nn, k=(tile&15)*32+c*8
//  Wout' [786432,1048576): 16 tiles of 32KB (512 cols); u: tile=u>>11, c=(u>>9)&3,
//      nn=u&511; n=nn, k=tile*32+c*8
//  W1'  [1048576,2097152): 128 tiles of 16KB; n=(tile>>4)*256+nn, k=(tile&15)*32+c*8
//  W2'  [2097152,3145728): 128 tiles of 16KB; n=(tile>>6)*256+nn, k=(tile&63)*32+c*8

// ---------- weights f32 -> bf16, k-tile-major repack ----------
__global__ void wcvt_kernel(const float* __restrict__ wqkv, const float* __restrict__ wout,
                            const float* __restrict__ w1f, const float* __restrict__ w2f,
                            bf16* __restrict__ o) {
    int i = blockIdx.x * blockDim.x + threadIdx.x;  // one 8-elem unit
    const float* s;
    int soff, doff;
    if (i < 98304) {  // Wqkv: [1536][512] -> 96 16KB tiles
        int u = i;
        int tile = u >> 10, c = (u >> 8) & 3, nn = u & 255;
        int n = (tile >> 4) * 256 + nn;
        int k = (tile & 15) * 32 + c * 8;
        s = wqkv; soff = n * 512 + k; doff = u * 8;
    } else if (i < 131072) {  // Wout: [512][512] -> 16 32KB tiles
        int u = i - 98304;
        int tile = u >> 11, c = (u >> 9) & 3, nn = u & 511;
        int k = tile * 32 + c * 8;
        s = wout; soff = nn * 512 + k; doff = 786432 + u * 8;
    } else if (i < 262144) {  // W1: [2048][512] -> 128 16KB tiles
        int u = i - 131072;
        int tile = u >> 10, c = (u >> 8) & 3, nn = u & 255;
        int n = (tile >> 4) * 256 + nn;
        int k = (tile & 15) * 32 + c * 8;
        s = w1f; soff = n * 512 + k; doff = 1048576 + u * 8;
    } else {  // W2: [512][2048] -> 128 16KB tiles (tile = cb*64 + t)
        int u = i - 262144;
        int tile = u >> 10, c = (u >> 8) & 3, nn = u & 255;
        int n = (tile >> 6) * 256 + nn;
        int k = (tile & 63) * 32 + c * 8;
        s = w2f; soff = n * 2048 + k; doff = 2097152 + u * 8;
    }
    float4 v0 = *(const float4*)(s + soff);
    float4 v1 = *(const float4*)(s + soff + 4);
    bf16x8 h = { (bf16)v0.x, (bf16)v0.y, (bf16)v0.z, (bf16)v0.w,
                 (bf16)v1.x, (bf16)v1.y, (bf16)v1.z, (bf16)v1.w };
    *(bf16x8*)(o + doff) = h;
}

// ---------- src f32 -> bf16 in place (row-aligned slot; wave per row) ----------
__global__ void xcvt_kernel(float* __restrict__ src) {
    int row = blockIdx.x * 4 + (threadIdx.x >> 6);
    int l = threadIdx.x & 63;
    float* rp = src + (size_t)row * 512 + l * 8;
    float4 v0 = *(const float4*)rp;
    float4 v1 = *(const float4*)(rp + 4);
    asm volatile("s_waitcnt vmcnt(0)" ::: "memory");  // all wave reads before any write
    bf16x8 h = { (bf16)v0.x, (bf16)v0.y, (bf16)v0.z, (bf16)v0.w,
                 (bf16)v1.x, (bf16)v1.y, (bf16)v1.z, (bf16)v1.w };
    *(bf16x8*)((bf16*)(src + (size_t)row * 512) + l * 8) = h;
}

// ---- N256 main loop: 3-deep, counted vmcnt(3), one phase/iter ----
// Needs STAGE_A(ib,t) (1 gload/wave) and STAGE_B2(ib,t,j) (j=0,1) in scope.
#define N256_LOOP(NT)                                                                  \
    int ib = 0;                                                                        \
    _Pragma("unroll 1")                                                                \
    for (int t = 0; t < (NT); ++t) {                                                   \
        int in2 = ib + 2; if (in2 >= 3) in2 -= 3;                                      \
        const uint32_t A0 = (uint32_t)ib * 8192u;                                      \
        const uint32_t B0 = 24576u + (uint32_t)ib * 16384u;                            \
        bf16x8 a[4], b[4];                                                             \
        _Pragma("unroll")                                                              \
        for (int i = 0; i < 4; ++i)                                                    \
            a[i] = *(const bf16x8*)(smem + A0 + quad * 2048 + (wm * 64 + i * 16 + l16) * 16); \
        _Pragma("unroll")                                                              \
        for (int nt = 0; nt < 4; ++nt)                                                 \
            b[nt] = *(const bf16x8*)(smem + B0 + quad * 4096 + (wn * 64 + nt * 16 + l16) * 16); \
        if (t + 2 < (NT)) { STAGE_A(in2, t + 2); STAGE_B2(in2, t + 2, 0); STAGE_B2(in2, t + 2, 1); } \
        _Pragma("unroll")                                                              \
        for (int nt = 0; nt < 4; ++nt)                                                 \
            _Pragma("unroll")                                                          \
            for (int i = 0; i < 4; ++i) acc[i][nt] = MFMA16(a[i], b[nt], acc[i][nt]);  \
        if (t + 2 < (NT)) asm volatile("s_waitcnt vmcnt(3)" ::: "memory");             \
        else              asm volatile("s_waitcnt vmcnt(0)" ::: "memory");             \
        __builtin_amdgcn_s_barrier();                                                  \
        ib = (ib == 2) ? 0 : ib + 1;                                                   \
    }

// ---- N512 phased main loop (R5 schedule, outproj) ----
#define PHASED_LOOP(NT)                                                                \
    int ib = 0;                                                                        \
    _Pragma("unroll 1")                                                                \
    for (int t = 0; t < (NT); ++t) {                                                   \
        int in2 = ib + 2; if (in2 >= 3) in2 -= 3;                                      \
        const uint32_t A0 = (uint32_t)ib * 8192u;                                      \
        const uint32_t B0 = 24576u + (uint32_t)ib * 32768u;                            \
        bf16x8 a[4], b[8];                                                             \
        /* ---- Phase 1 ---- */                                                        \
        _Pragma("unroll")                                                              \
        for (int i = 0; i < 4; ++i)                                                    \
            a[i] = *(const bf16x8*)(smem + A0 + quad * 2048 + (wm * 64 + i * 16 + l16) * 16); \
        _Pragma("unroll")                                                              \
        for (int nt = 0; nt < 4; ++nt)                                                 \
            b[nt] = *(const bf16x8*)(smem + B0 + quad * 8192 + (wn * 128 + nt * 16 + l16) * 16); \
        if (t + 2 < (NT)) { STAGE_A(in2, t + 2); STAGE_B(in2, t + 2, 0); }             \
        __builtin_amdgcn_s_barrier();                                                  \
        asm volatile("s_waitcnt lgkmcnt(0)" ::: "memory");                             \
        __builtin_amdgcn_sched_barrier(0);                                             \
        __builtin_amdgcn_s_setprio(1);                                                 \
        _Pragma("unroll")                                                              \
        for (int nt = 0; nt < 4; ++nt)                                                 \
            _Pragma("unroll")                                                          \
            for (int i = 0; i < 4; ++i) acc[i][nt] = MFMA16(a[i], b[nt], acc[i][nt]);  \
        __builtin_amdgcn_s_setprio(0);                                                 \
        __builtin_amdgcn_s_barrier();                                                  \
        /* ---- Phase 2 ---- */                                                        \
        _Pragma("unroll")                                                              \
        for (int nt = 4; nt < 8; ++nt)                                                 \
            b[nt] = *(const bf16x8*)(smem + B0 + quad * 8192 + (wn * 128 + nt * 16 + l16) * 16); \
        if (t + 2 < (NT)) { STAGE_B(in2, t + 2, 1); STAGE_B(in2, t + 2, 2); STAGE_B(in2, t + 2, 3); } \
        __builtin_amdgcn_s_barrier();                                                  \
        asm volatile("s_waitcnt lgkmcnt(0)" ::: "memory");                             \
        __builtin_amdgcn_sched_barrier(0);                                             \
        __builtin_amdgcn_s_setprio(1);                                                 \
        _Pragma("unroll")                                                              \
        for (int nt = 4; nt < 8; ++nt)                                                 \
            _Pragma("unroll")                                                          \
            for (int i = 0; i < 4; ++i) acc[i][nt] = MFMA16(a[i], b[nt], acc[i][nt]);  \
        __builtin_amdgcn_s_setprio(0);                                                 \
        if (t + 2 < (NT)) asm volatile("s_waitcnt vmcnt(5)" ::: "memory");             \
        else              asm volatile("s_waitcnt vmcnt(0)" ::: "memory");             \
        __builtin_amdgcn_s_barrier();                                                  \
        ib = (ib == 2) ? 0 : ib + 1;                                                   \
    }

// ---------- qkv GEMM v5: M=32768 N=1536 K=512; 128x256 tile, grid (256,6) ----------
extern "C" __global__ __launch_bounds__(512, 4)
void qkv_kernel(const char* __restrict__ xb, const char* __restrict__ Wqkvp,
                const float* __restrict__ bqkv, char* __restrict__ qOb,
                char* __restrict__ kvb) {
    extern __shared__ char smem[];
    const int tid = threadIdx.x;
    const int w = tid >> 6, lane = tid & 63, l16 = lane & 15, quad = lane >> 4;
    const int wm = w >> 2, wn = w & 3;
    const int mb = blockIdx.x, cb = blockIdx.y;

    f32x4 acc[4][4];
#pragma unroll
    for (int i = 0; i < 4; ++i)
#pragma unroll
        for (int nt = 0; nt < 4; ++nt) acc[i][nt] = (f32x4){0.f, 0.f, 0.f, 0.f};

#define STAGE_A(ib_, t_)                                                               \
    {                                                                                  \
        int ca = w >> 1, rg = w & 1;                                                   \
        gload16(xb + (size_t)(mb * 128 + rg * 64 + lane) * 2048 + (t_) * 64 + ca * 16, \
                smem + (uint32_t)(ib_) * 8192u + ca * 2048 + rg * 1024);               \
    }
#define STAGE_B2(ib_, t_, j_)                                                          \
    {                                                                                  \
        int idx = w * 2 + (j_), c = idx >> 2, ng = idx & 3;                            \
        gload16(Wqkvp + (size_t)(cb * 16 + (t_)) * 16384 + c * 4096 + ng * 1024 + lane * 16, \
                smem + 24576u + (uint32_t)(ib_) * 16384u + (uint32_t)c * 4096 + (uint32_t)ng * 1024); \
    }

    STAGE_A(0, 0); STAGE_B2(0, 0, 0); STAGE_B2(0, 0, 1);
    STAGE_A(1, 1); STAGE_B2(1, 1, 0); STAGE_B2(1, 1, 1);
    asm volatile("s_waitcnt vmcnt(3)" ::: "memory");
    __builtin_amdgcn_s_barrier();

    N256_LOOP(16)
#undef STAGE_A
#undef STAGE_B2

    // epilogue: bias; per-i 16x64 transpose through 2KB wave scratch (dead B region)
    const uint32_t sb = 24576u + (uint32_t)w * 2048u;
#pragma unroll
    for (int i = 0; i < 4; ++i) {
#pragma unroll
        for (int nt = 0; nt < 4; ++nt) {
            float bb = bqkv[cb * 256 + wn * 64 + nt * 16 + l16];
#pragma unroll
            for (int r = 0; r < 4; ++r)
                *(bf16*)(smem + swz(sb, quad * 4 + r, 128, (nt * 16 + l16) * 2)) =
                    (bf16)(acc[i][nt][r] + bb);
        }
        asm volatile("s_waitcnt lgkmcnt(0)" ::: "memory");
#pragma unroll
        for (int t2 = 0; t2 < 2; ++t2) {
            int row = t2 * 8 + (lane >> 3), ch = lane & 7;
            bf16x8 v = *(bf16x8*)(smem + swz(sb, row, 128, ch * 16));
            size_t row_g = (size_t)(mb * 128 + wm * 64 + i * 16 + row);
            int cbyte = wn * 128 + ch * 16;  // within this cb's 512B col-slice
            if (cb < 2)      *(bf16x8*)(qOb + row_g * 1024 + cb * 512 + cbyte) = v;
            else if (cb < 4) *(bf16x8*)(kvb + row_g * 2048 + (cb - 2) * 512 + cbyte) = v;
            else             *(bf16x8*)(kvb + row_g * 2048 + 1024 + (cb - 4) * 512 + cbyte) = v;
        }
        asm volatile("s_waitcnt lgkmcnt(0)" ::: "memory");
    }
}

// ---------- attention: one block per (window, head) ----------
#define AVT 0u       // vT 64x128 bf16 rs=256B (16KB)
#define ASCR 16384u  // 8 waves x 2KB transpose scratch
extern "C" __global__ __launch_bounds__(512, 4)
void attn_kernel(char* __restrict__ qOb, const char* __restrict__ kvb) {
    extern __shared__ char smem[];
    const int tid = threadIdx.x;
    const int wid = tid >> 6, lane = tid & 63, l16 = lane & 15, quad = lane >> 4;
    const int win = blockIdx.x >> 3, head = blockIdx.x & 7;
    const size_t wrow0 = (size_t)win * 128;
    f32x4 zero4 = { 0.f, 0.f, 0.f, 0.f };

    // stage vT[dim][key] from v rows
    {
        int key = tid >> 2, d0 = (tid & 3) * 16;
        const char* vs = kvb + (wrow0 + key) * 2048 + 1024 + head * 128 + d0 * 2;
#pragma unroll
        for (int j = 0; j < 2; ++j) {
            bf16x8 v = *(const bf16x8*)(vs + j * 16);
#pragma unroll
            for (int e = 0; e < 8; ++e)
                *(bf16*)(smem + swz(AVT, d0 + j * 8 + e, 256, key * 2)) = v[e];
        }
    }
    __syncthreads();  // only barrier in this kernel

    // q fragments (A layout, direct from global)
    bf16x8 qf[2];
#pragma unroll
    for (int ks = 0; ks < 2; ++ks)
        qf[ks] = *(const bf16x8*)(qOb + (wrow0 + wid * 16 + l16) * 1024 + head * 128 + ks * 64 + quad * 16);

    // scores (k B-frags direct from global)
    f32x4 sa[8];
#pragma unroll
    for (int nt = 0; nt < 8; ++nt) sa[nt] = zero4;
#pragma unroll
    for (int nt = 0; nt < 8; ++nt)
#pragma unroll
        for (int ks = 0; ks < 2; ++ks) {
            bf16x8 kb = *(const bf16x8*)(kvb + (wrow0 + nt * 16 + l16) * 2048 + head * 128 + ks * 64 + quad * 16);
            sa[nt] = MFMA16(qf[ks], kb, sa[nt]);
        }
#pragma unroll
    for (int nt = 0; nt < 8; ++nt) sa[nt] *= 0.125f;
#pragma unroll
    for (int r = 0; r < 4; ++r) {
        float m = sa[0][r];
#pragma unroll
        for (int nt = 1; nt < 8; ++nt) m = fmaxf(m, sa[nt][r]);
#pragma unroll
        for (int sft = 1; sft < 16; sft <<= 1) m = fmaxf(m, __shfl_xor(m, sft, 64));
        float s = 0.f;
#pragma unroll
        for (int nt = 0; nt < 8; ++nt) {
            float e = __expf(sa[nt][r] - m);
            sa[nt][r] = e;
            s += e;
        }
#pragma unroll
        for (int sft = 1; sft < 16; sft <<= 1) s += __shfl_xor(s, sft, 64);
        float inv = 1.0f / s;
#pragma unroll
        for (int nt = 0; nt < 8; ++nt) sa[nt][r] *= inv;
    }

    // P C->A transpose through wave-private scratch
    const uint32_t sb = ASCR + (uint32_t)wid * 2048;
    bf16x8 pf[4];
#pragma unroll
    for (int hf = 0; hf < 2; ++hf) {
#pragma unroll
        for (int nt = 0; nt < 4; ++nt)
#pragma unroll
            for (int r = 0; r < 4; ++r)
                *(bf16*)(smem + swz(sb, quad * 4 + r, 128, (nt * 16 + l16) * 2)) = (bf16)sa[hf * 4 + nt][r];
        asm volatile("s_waitcnt lgkmcnt(0)" ::: "memory");
#pragma unroll
        for (int ks = 0; ks < 2; ++ks)
            pf[hf * 2 + ks] = *(bf16x8*)(smem + swz(sb, l16, 128, ks * 64 + quad * 16));
        asm volatile("s_waitcnt lgkmcnt(0)" ::: "memory");
    }

    // O = P @ V
    f32x4 ov[4];
#pragma unroll
    for (int nt = 0; nt < 4; ++nt) {
        ov[nt] = zero4;
#pragma unroll
        for (int ks = 0; ks < 4; ++ks) {
            bf16x8 vb = *(bf16x8*)(smem + swz(AVT, nt * 16 + l16, 256, ks * 64 + quad * 16));
            ov[nt] = MFMA16(pf[ks], vb, ov[nt]);
        }
    }
    // O store via transpose: two 32-col halves through 2KB wave scratch (rs=128)
#pragma unroll
    for (int hf = 0; hf < 2; ++hf) {
#pragma unroll
        for (int nt = 0; nt < 2; ++nt)
#pragma unroll
            for (int r = 0; r < 4; ++r)
                *(bf16*)(smem + swz(sb, quad * 4 + r, 128, (nt * 16 + l16) * 2)) = (bf16)ov[hf * 2 + nt][r];
        asm volatile("s_waitcnt lgkmcnt(0)" ::: "memory");
        {
            int row = lane >> 2, ch = lane & 3;
            bf16x8 v = *(bf16x8*)(smem + swz(sb, row, 128, ch * 16));
            *(bf16x8*)(qOb + (wrow0 + wid * 16 + row) * 1024 + head * 128 + hf * 64 + ch * 16) = v;
        }
        asm volatile("s_waitcnt lgkmcnt(0)" ::: "memory");
    }
}

// ---------- out-proj v4 + residual + LN1: M=32768 N=512 K=512 ----------
extern "C" __global__ __launch_bounds__(512, 2)
void outproj_kernel(char* __restrict__ srcb, const char* __restrict__ qOb,
                    const char* __restrict__ Woutp, const float* __restrict__ bout,
                    const float* __restrict__ g1, const float* __restrict__ be1) {
    extern __shared__ char smem[];
    const int tid = threadIdx.x;
    const int w = tid >> 6, lane = tid & 63, l16 = lane & 15, quad = lane >> 4;
    const int wm = w >> 2, wn = w & 3;
    const int mb = blockIdx.x;

    f32x4 acc[4][8];
#pragma unroll
    for (int i = 0; i < 4; ++i)
#pragma unroll
        for (int nt = 0; nt < 8; ++nt) acc[i][nt] = (f32x4){0.f, 0.f, 0.f, 0.f};

#define STAGE_A(ib_, t_)                                                               \
    {                                                                                  \
        int ca = w >> 1, rg = w & 1;                                                   \
        gload16(qOb + (size_t)(mb * 128 + rg * 64 + lane) * 1024 + (t_) * 64 + ca * 16, \
                smem + (uint32_t)(ib_) * 8192u + ca * 2048 + rg * 1024);               \
    }
#define STAGE_B(ib_, t_, j_)                                                           \
    {                                                                                  \
        int idx = w * 4 + (j_), c = idx >> 3, ng = idx & 7;                            \
        gload16(Woutp + (size_t)(t_) * 32768 + c * 8192 + ng * 1024 + lane * 16,       \
                smem + 24576u + (uint32_t)(ib_) * 32768u + (uint32_t)c * 8192 + (uint32_t)ng * 1024); \
    }

    STAGE_A(0, 0); STAGE_B(0, 0, 0); STAGE_B(0, 0, 1); STAGE_B(0, 0, 2); STAGE_B(0, 0, 3);
    STAGE_A(1, 1); STAGE_B(1, 1, 0); STAGE_B(1, 1, 1); STAGE_B(1, 1, 2); STAGE_B(1, 1, 3);
    asm volatile("s_waitcnt vmcnt(5)" ::: "memory");
    __builtin_amdgcn_s_barrier();

    PHASED_LOOP(16)
#undef STAGE_A
#undef STAGE_B

    // ---- bias + residual(x bf16) ----
#pragma unroll
    for (int nt = 0; nt < 8; ++nt) {
        int col = wn * 128 + nt * 16 + l16;
        float bb = bout[col];
#pragma unroll
        for (int i = 0; i < 4; ++i)
#pragma unroll
            for (int r = 0; r < 4; ++r) {
                int row = mb * 128 + wm * 64 + i * 16 + quad * 4 + r;
                float xv = (float)*(const bf16*)(srcb + (size_t)row * 2048 + col * 2);
                acc[i][nt][r] += bb + xv;
            }
    }
    // per-(row, wave) partials over this wave's 128 cols
    float ps[4][4], ps2[4][4];
#pragma unroll
    for (int i = 0; i < 4; ++i)
#pragma unroll
        for (int r = 0; r < 4; ++r) {
            float s = 0.f, s2 = 0.f;
#pragma unroll
            for (int nt = 0; nt < 8; ++nt) {
                float v = acc[i][nt][r];
                s += v;
                s2 += v * v;
            }
#pragma unroll
            for (int sft = 1; sft < 16; sft <<= 1) {
                s += __shfl_xor(s, sft, 64);
                s2 += __shfl_xor(s2, sft, 64);
            }
            ps[i][r] = s;
            ps2[i][r] = s2;
        }
    // cross-wave reduce via LDS scratch (dead A-buf): [128 rows][4 wn][2 f32]
    if (l16 == 0) {
#pragma unroll
        for (int i = 0; i < 4; ++i)
#pragma unroll
            for (int r = 0; r < 4; ++r) {
                int row_l = wm * 64 + i * 16 + quad * 4 + r;
                *(float*)(smem + row_l * 32 + wn * 8) = ps[i][r];
                *(float*)(smem + row_l * 32 + wn * 8 + 4) = ps2[i][r];
            }
    }
    __syncthreads();
    // per-i: LN1 + 16x128 transpose-store of bf16 x1 into srcb[1024:2048)
    const uint32_t sb = 24576u + (uint32_t)w * 4096u;  // dead B region
#pragma unroll
    for (int i = 0; i < 4; ++i) {
#pragma unroll
        for (int r = 0; r < 4; ++r) {
            int row_l = wm * 64 + i * 16 + quad * 4 + r;
            float S = 0.f, S2 = 0.f;
#pragma unroll
            for (int w4 = 0; w4 < 4; ++w4) {
                S += *(const float*)(smem + row_l * 32 + w4 * 8);
                S2 += *(const float*)(smem + row_l * 32 + w4 * 8 + 4);
            }
            float mu = S * (1.0f / 512.0f);
            float var = S2 * (1.0f / 512.0f) - mu * mu;
            float rstd = rsqrtf(var + 1e-5f);
#pragma unroll
            for (int nt = 0; nt < 8; ++nt) {
                int col = wn * 128 + nt * 16 + l16;
                float v = (acc[i][nt][r] - mu) * rstd * g1[col] + be1[col];
                *(bf16*)(smem + swz(sb, quad * 4 + r, 256, (nt * 16 + l16) * 2)) = (bf16)v;
            }
        }
        asm volatile("s_waitcnt lgkmcnt(0)" ::: "memory");
#pragma unroll
        for (int j = 0; j < 4; ++j) {
            int uu = j * 64 + lane;
            int row = uu >> 4, ch = uu & 15;
            bf16x8 v = *(bf16x8*)(smem + swz(sb, row, 256, ch * 16));
            *(bf16x8*)(srcb + (size_t)(mb * 128 + wm * 64 + i * 16 + row) * 2048 + 1024 +
                       wn * 256 + ch * 16) = v;
        }
        asm volatile("s_waitcnt lgkmcnt(0)" ::: "memory");
    }
}

// ---------- FF1 v6: M=32768 N=2048 K=512; 128x256 tile, grid (256,8) ----------
extern "C" __global__ __launch_bounds__(512, 4)
void ff1_kernel(char* __restrict__ srcb, const char* __restrict__ W1p,
                const float* __restrict__ b1, char* __restrict__ doutb,
                char* __restrict__ wsOb) {
    extern __shared__ char smem[];
    const int tid = threadIdx.x;
    const int w = tid >> 6, lane = tid & 63, l16 = lane & 15, quad = lane >> 4;
    const int wm = w >> 2, wn = w & 3;
    const int mb = blockIdx.x, cb = blockIdx.y;

    f32x4 acc[4][4];
#pragma unroll
    for (int i = 0; i < 4; ++i)
#pragma unroll
        for (int nt = 0; nt < 4; ++nt) acc[i][nt] = (f32x4){0.f, 0.f, 0.f, 0.f};

#define STAGE_A(ib_, t_)                                                               \
    {                                                                                  \
        int ca = w >> 1, rg = w & 1;                                                   \
        gload16(srcb + (size_t)(mb * 128 + rg * 64 + lane) * 2048 + 1024 + (t_) * 64 + ca * 16, \
                smem + (uint32_t)(ib_) * 8192u + ca * 2048 + rg * 1024);               \
    }
#define STAGE_B2(ib_, t_, j_)                                                          \
    {                                                                                  \
        int idx = w * 2 + (j_), c = idx >> 2, ng = idx & 3;                            \
        gload16(W1p + (size_t)(cb * 16 + (t_)) * 16384 + c * 4096 + ng * 1024 + lane * 16, \
                smem + 24576u + (uint32_t)(ib_) * 16384u + (uint32_t)c * 4096 + (uint32_t)ng * 1024); \
    }

    STAGE_A(0, 0); STAGE_B2(0, 0, 0); STAGE_B2(0, 0, 1);
    STAGE_A(1, 1); STAGE_B2(1, 1, 0); STAGE_B2(1, 1, 1);
    asm volatile("s_waitcnt vmcnt(3)" ::: "memory");
    __builtin_amdgcn_s_barrier();

    N256_LOOP(16)
#undef STAGE_A
#undef STAGE_B2

    // epilogue: bias+relu; per-i 16x64 transpose through 2KB wave scratch
    const uint32_t sb = 24576u + (uint32_t)w * 2048u;
#pragma unroll
    for (int i = 0; i < 4; ++i) {
#pragma unroll
        for (int nt = 0; nt < 4; ++nt) {
            float bb = b1[cb * 256 + wn * 64 + nt * 16 + l16];
#pragma unroll
            for (int r = 0; r < 4; ++r)
                *(bf16*)(smem + swz(sb, quad * 4 + r, 128, (nt * 16 + l16) * 2)) =
                    (bf16)fmaxf(acc[i][nt][r] + bb, 0.0f);
        }
        asm volatile("s_waitcnt lgkmcnt(0)" ::: "memory");
#pragma unroll
        for (int t2 = 0; t2 < 2; ++t2) {
            int row = t2 * 8 + (lane >> 3), ch = lane & 7;
            bf16x8 v = *(bf16x8*)(smem + swz(sb, row, 128, ch * 16));
            size_t row_g = (size_t)(mb * 128 + wm * 64 + i * 16 + row);
            int cbyte = wn * 128 + ch * 16;  // within this cb's 512B col-slice
            if (cb < 4)      *(bf16x8*)(doutb + row_g * 2048 + cb * 512 + cbyte) = v;
            else if (cb < 6) *(bf16x8*)(srcb + row_g * 2048 + (cb - 4) * 512 + cbyte) = v;
            else             *(bf16x8*)(wsOb + row_g * 1024 + (cb - 6) * 512 + cbyte) = v;
        }
        asm volatile("s_waitcnt lgkmcnt(0)" ::: "memory");
    }
}

// ---------- FF2 v8: M=32768 N=512 K=2048; 128x256 tile, grid (256,2) ----------
// N256 template (2 blocks/CU). Epilogue: y = acc + b2 + x1 -> f32 doutb.
// LN2 de-fused into ln2_kernel.
extern "C" __global__ __launch_bounds__(512, 4)
void ff2_kernel(char* __restrict__ doutb, const char* __restrict__ srcb,
                const char* __restrict__ wsOb, const char* __restrict__ W2p,
                const float* __restrict__ b2) {
    extern __shared__ char smem[];
    const int tid = threadIdx.x;
    const int w = tid >> 6, lane = tid & 63, l16 = lane & 15, quad = lane >> 4;
    const int wm = w >> 2, wn = w & 3;
    const int mb = blockIdx.x, cb = blockIdx.y;

    f32x4 acc[4][4];
#pragma unroll
    for (int i = 0; i < 4; ++i)
#pragma unroll
        for (int nt = 0; nt < 4; ++nt) acc[i][nt] = (f32x4){0.f, 0.f, 0.f, 0.f};

#define STAGE_A(ib_, t_)                                                               \
    {                                                                                  \
        const char* hb; int rstride, koffb;                                            \
        if ((t_) < 32)      { hb = doutb; rstride = 2048; koffb = (t_) * 64; }         \
        else if ((t_) < 48) { hb = srcb;  rstride = 2048; koffb = ((t_) - 32) * 64; }  \
        else                { hb = wsOb;  rstride = 1024; koffb = ((t_) - 48) * 64; }  \
        int ca = w >> 1, rg = w & 1;                                                   \
        gload16(hb + (size_t)(mb * 128 + rg * 64 + lane) * rstride + koffb + ca * 16,  \
                smem + (uint32_t)(ib_) * 8192u + ca * 2048 + rg * 1024);               \
    }
#define STAGE_B2(ib_, t_, j_)                                                          \
    {                                                                                  \
        int idx = w * 2 + (j_), c = idx >> 2, ng = idx & 3;                            \
        gload16(W2p + (size_t)(cb * 64 + (t_)) * 16384 + c * 4096 + ng * 1024 + lane * 16, \
                smem + 24576u + (uint32_t)(ib_) * 16384u + (uint32_t)c * 4096 + (uint32_t)ng * 1024); \
    }

    STAGE_A(0, 0); STAGE_B2(0, 0, 0); STAGE_B2(0, 0, 1);
    STAGE_A(1, 1); STAGE_B2(1, 1, 0); STAGE_B2(1, 1, 1);
    asm volatile("s_waitcnt vmcnt(3)" ::: "memory");
    __builtin_amdgcn_s_barrier();

    N256_LOOP(64)
#undef STAGE_A
#undef STAGE_B2

    // epilogue: bias + residual(x1 bf16) -> f32 y into doutb (own rows only;
    // all this block's h reads from doutb finished above)
#pragma unroll
    for (int nt = 0; nt < 4; ++nt) {
        int col = cb * 256 + wn * 64 + nt * 16 + l16;
        float bb = b2[col];
#pragma unroll
        for (int i = 0; i < 4; ++i)
#pragma unroll
            for (int r = 0; r < 4; ++r) {
                int row = mb * 128 + wm * 64 + i * 16 + quad * 4 + r;
                float x1v = (float)*(const bf16*)(srcb + (size_t)row * 2048 + 1024 + col * 2);
                *(float*)(doutb + (size_t)row * 2048 + col * 4) = acc[i][nt][r] + bb + x1v;
            }
    }
}

// ---------- LN2: in-place row layernorm on f32 y (wave per row) ----------
extern "C" __global__ __launch_bounds__(256)
void ln2_kernel(float* __restrict__ y, const float* __restrict__ g2,
                const float* __restrict__ be2) {
    int row = blockIdx.x * 4 + (threadIdx.x >> 6);
    int lane = threadIdx.x & 63;
    float* rp = y + (size_t)row * 512 + lane * 8;
    float4 v0 = *(const float4*)rp;
    float4 v1 = *(const float4*)(rp + 4);
    float s = v0.x + v0.y + v0.z + v0.w + v1.x + v1.y + v1.z + v1.w;
    float s2 = v0.x * v0.x + v0.y * v0.y + v0.z * v0.z + v0.w * v0.w +
               v1.x * v1.x + v1.y * v1.y + v1.z * v1.z + v1.w * v1.w;
#pragma unroll
    for (int sft = 1; sft < 64; sft <<= 1) {
        s += __shfl_xor(s, sft, 64);
        s2 += __shfl_xor(s2, sft, 64);
    }
    float mu = s * (1.0f / 512.0f);
    float var = s2 * (1.0f / 512.0f) - mu * mu;
    float rstd = rsqrtf(var + 1e-5f);
    const float* gp = g2 + lane * 8;
    const float* bp = be2 + lane * 8;
    float4 o0, o1;
    o0.x = (v0.x - mu) * rstd * gp[0] + bp[0];
    o0.y = (v0.y - mu) * rstd * gp[1] + bp[1];
    o0.z = (v0.z - mu) * rstd * gp[2] + bp[2];
    o0.w = (v0.w - mu) * rstd * gp[3] + bp[3];
    o1.x = (v1.x - mu) * rstd * gp[4] + bp[4];
    o1.y = (v1.y - mu) * rstd * gp[5] + bp[5];
    o1.z = (v1.z - mu) * rstd * gp[6] + bp[6];
    o1.w = (v1.w - mu) * rstd * gp[7] + bp[7];
    *(float4*)rp = o0;
    *(float4*)(rp + 4) = o1;
}

extern "C" void kernel_launch(void* const* d_in, const int* in_sizes, int n_in,
                              void* d_out, int out_size, void* d_ws, size_t ws_size,
                              hipStream_t stream) {
    (void)in_sizes; (void)n_in; (void)out_size; (void)ws_size;
    float* src = (float*)d_in[0];
    const float* ipw = (const float*)d_in[1];
    const float* ipb = (const float*)d_in[2];
    const float* ow  = (const float*)d_in[3];
    const float* ob  = (const float*)d_in[4];
    const float* g1  = (const float*)d_in[5];
    const float* be1 = (const float*)d_in[6];
    const float* w1  = (const float*)d_in[7];
    const float* b1  = (const float*)d_in[8];
    const float* w2  = (const float*)d_in[9];
    const float* b2  = (const float*)d_in[10];
    const float* g2  = (const float*)d_in[11];
    const float* be2 = (const float*)d_in[12];
    bf16* ws = (bf16*)d_ws;
    char* srcb = (char*)src;
    char* doutb = (char*)d_out;
    char* qOb = (char*)d_ws + 6291456;  // 33.5 MB q/O/h-tail region

    wcvt_kernel<<<1536, 256, 0, stream>>>(ipw, ow, w1, w2, ws);
    xcvt_kernel<<<8192, 256, 0, stream>>>(src);

    hipFuncSetAttribute((const void*)qkv_kernel, hipFuncAttributeMaxDynamicSharedMemorySize, 73728);
    hipFuncSetAttribute((const void*)attn_kernel, hipFuncAttributeMaxDynamicSharedMemorySize, 32768);
    hipFuncSetAttribute((const void*)outproj_kernel, hipFuncAttributeMaxDynamicSharedMemorySize, 122880);
    hipFuncSetAttribute((const void*)ff1_kernel, hipFuncAttributeMaxDynamicSharedMemorySize, 73728);
    hipFuncSetAttribute((const void*)ff2_kernel, hipFuncAttributeMaxDynamicSharedMemorySize, 73728);

    qkv_kernel<<<dim3(256, 6), 512, 73728, stream>>>(srcb, (const char*)ws, ipb, qOb, doutb);
    attn_kernel<<<2048, 512, 32768, stream>>>(qOb, doutb);
    outproj_kernel<<<256, 512, 122880, stream>>>(srcb, qOb, (const char*)(ws + 786432), ob, g1, be1);
    ff1_kernel<<<dim3(256, 8), 512, 73728, stream>>>(srcb, (const char*)(ws + 1048576), b1, doutb, qOb);
    ff2_kernel<<<dim3(256, 2), 512, 73728, stream>>>(doutb, srcb, qOb, (const char*)(ws + 2097152), b2);
    ln2_kernel<<<8192, 256, 0, stream>>>((float*)doutb, g2, be2);
}